// Round 14
// baseline (78.197 us; speedup 1.0000x reference)
//
#include <hip/hip_runtime.h>

typedef _Float16 half4 __attribute__((ext_vector_type(4)));
typedef _Float16 half8 __attribute__((ext_vector_type(8)));
typedef float floatx4 __attribute__((ext_vector_type(4)));

#define U_RESV 400
#define A_RESV 50

#define UHALVES (U_RESV * U_RESV * 8)   // 1,280,000
#define AHALVES (A_RESV * A_RESV * 8)   // 20,000
#define WOFF    (UHALVES + 2 * AHALVES) // weights offset (halves)
// W0 32x28 (cols>=24 zero) | W1 32x36 | W2 32x36 | W3 16x36 (rows>=3 zero)
#define W0OFF   0
#define W1OFF   896
#define W2OFF   2048
#define W3OFF   3200
#define WTOT    3776                    // halves; 7552 B = 472 x 16 B

__device__ __forceinline__ float clamp01(float x) { return fminf(fmaxf(x, 0.0f), 1.0f); }

__device__ __forceinline__ floatx4 mfma16(half4 a, half4 b, floatx4 c) {
    return __builtin_amdgcn_mfma_f32_16x16x16f16(a, b, c, 0, 0, 0);
}
__device__ __forceinline__ half4 zero4() {
    half4 h; h[0] = h[1] = h[2] = h[3] = (_Float16)0.f; return h;
}
__device__ __forceinline__ half4 relu4(half4 v) {
#if __has_builtin(__builtin_elementwise_max)
    return __builtin_elementwise_max(v, zero4());
#else
    half4 r;
#pragma unroll
    for (int i = 0; i < 4; ++i) r[i] = v[i] > (_Float16)0.f ? v[i] : (_Float16)0.f;
    return r;
#endif
}

__device__ __forceinline__ void cvt_chunk(const float* __restrict__ src,
                                          _Float16* __restrict__ dst, int i) {
    float4 a = *(const float4*)(src + (size_t)i * 8);
    float4 b = *(const float4*)(src + (size_t)i * 8 + 4);
    half8 h;
    h[0] = (_Float16)a.x; h[1] = (_Float16)a.y; h[2] = (_Float16)a.z; h[3] = (_Float16)a.w;
    h[4] = (_Float16)b.x; h[5] = (_Float16)b.y; h[6] = (_Float16)b.z; h[7] = (_Float16)b.w;
    *(half8*)(dst + (size_t)i * 8) = h;
}

__device__ __forceinline__ void wblob_fill(const float* __restrict__ W0,
                                           const float* __restrict__ W1,
                                           const float* __restrict__ W2,
                                           const float* __restrict__ W3,
                                           _Float16* __restrict__ w, int tid, int nthr) {
    for (int i = tid; i < WTOT; i += nthr) {
        float v;
        if (i < W1OFF) {
            int r = i / 28, c = i - r * 28;
            v = (c < 24) ? W0[r * 24 + c] : 0.f;
        } else if (i < W2OFF) {
            int j = i - W1OFF, r = j / 36, c = j - r * 36;
            v = (c < 32) ? W1[r * 32 + c] : 0.f;
        } else if (i < W3OFF) {
            int j = i - W2OFF, r = j / 36, c = j - r * 36;
            v = (c < 32) ? W2[r * 32 + c] : 0.f;
        } else {
            int j = i - W3OFF, r = j / 36, c = j - r * 36;
            v = (r < 3 && c < 32) ? W3[r * 32 + c] : 0.f;
        }
        w[i] = (_Float16)v;
    }
}

// ---- prep: all planes + weights -> f16 blob in ws ----
__global__ __launch_bounds__(256) void pconv_kernel(
    const float* __restrict__ u_plane, const float* __restrict__ h_plane,
    const float* __restrict__ d_plane, const float* __restrict__ W0,
    const float* __restrict__ W1, const float* __restrict__ W2,
    const float* __restrict__ W3, _Float16* __restrict__ dst) {
    const int gid = blockIdx.x * 256 + threadIdx.x;
    const int gsz = gridDim.x * 256;
    for (int i = gid; i < UHALVES / 8; i += gsz) cvt_chunk(u_plane, dst, i);
    for (int i = gid; i < AHALVES / 8; i += gsz) cvt_chunk(h_plane, dst + UHALVES, i);
    for (int i = gid; i < AHALVES / 8; i += gsz) cvt_chunk(d_plane, dst + UHALVES + AHALVES, i);
    if (blockIdx.x == 0) wblob_fill(W0, W1, W2, W3, dst + WOFF, threadIdx.x, 256);
}

__global__ __launch_bounds__(256) void wprep_kernel(
    const float* __restrict__ W0, const float* __restrict__ W1,
    const float* __restrict__ W2, const float* __restrict__ W3,
    _Float16* __restrict__ wdst) {
    wblob_fill(W0, W1, W2, W3, wdst, threadIdx.x, 256);
}

// R14: R13 with ZERO block-wide barriers. Weight-LDS handoff is wave-
// redundant: every wave loads the full 7.4KB blob (coalesced) and writes it
// to wl itself; concurrent same-value LDS writes are benign, and each wave's
// own lgkmcnt(0) (before MLP reads) suffices. Waves become fully independent
// -> natural phase staggering -> TA/VALU overlap across resident waves
// (R13 post-mortem: block s_barrier phase-locked all 8 waves into the same
// load-shadow; occupancy 55%, VALUBusy 33%, waves ~96% stalled).
// MFMA maps (verified R4..R13, 16x16x16 f16):
//   A: lane 16q+c holds A[row=c][k=4q+e];  B: lane 16q+c holds B[k=4q+e][col=c]
//   D: lane 16q+c reg r holds D[row=4q+r][col=c]
// Chain identity: D reg r == next-layer B elem e. MLP chains in registers;
// wave owns 64 points (j-tiles 0..3).

template <bool F16P>
__global__ __launch_bounds__(512, 2) void tpmlp_kernel(
    const float* __restrict__ x,
    const void* __restrict__ u_tex,
    const void* __restrict__ h_tex,
    const void* __restrict__ d_tex,
    const _Float16* __restrict__ wsw,
    float* __restrict__ out) {
    const int tid  = threadIdx.x;
    const int lane = tid & 63;
    const int wv   = tid >> 6;
    const int q    = lane >> 4;
    const int c15  = lane & 15;

    __shared__ __align__(16) _Float16 fl[512 * 28];   // feat: 512 pts x 28 (56 B stride)
    __shared__ __align__(16) _Float16 wl[WTOT];

    // ---- 1. x loads (critical path -> first) ----
    const size_t P = (size_t)blockIdx.x * 512 + tid;
    const float2* xp = (const float2*)(x + P * 6);
    float2 p01v = xp[0], p23v = xp[1], p45v = xp[2];

    // ---- 2. per-wave weight staging loads (full blob per wave, coalesced) ----
    uint4 wc0, wc1, wc2, wc3, wc4, wc5, wc6, wc7;
    {
        const uint4* src = (const uint4*)wsw;
        wc0 = src[lane];
        wc1 = src[lane + 64];
        wc2 = src[lane + 128];
        wc3 = src[lane + 192];
        wc4 = src[lane + 256];
        wc5 = src[lane + 320];
        wc6 = src[lane + 384];
        if (lane < 472 - 448) wc7 = src[lane + 448];
    }

    // ---- 3. gather addresses (once per point; hides blob latency) ----
    int oU0, oU1, oU2, oU3;  float uw00, uw10, uw01, uw11;
    {
        float u = clamp01(p01v.x) * (float)(U_RESV - 1);
        float v = clamp01(p01v.y) * (float)(U_RESV - 1);
        float x0f = floorf(u), y0f = floorf(v);
        int x0 = (int)x0f, y0 = (int)y0f;
        int x1 = min(x0 + 1, U_RESV - 1), y1 = min(y0 + 1, U_RESV - 1);
        float ur = u - x0f, vr = v - y0f;
        uw00 = (1.0f - ur) * (1.0f - vr); uw10 = ur * (1.0f - vr);
        uw01 = (1.0f - ur) * vr;          uw11 = ur * vr;
        oU0 = (y0 * U_RESV + x0) * 8;
        oU1 = (y0 * U_RESV + x1) * 8;
        oU2 = (y1 * U_RESV + x0) * 8;
        oU3 = (y1 * U_RESV + x1) * 8;
    }
    int oH0, oH1, oH2, oH3;  float hw00, hw10, hw01, hw11;
    {
        float uu = p23v.y, vv = p23v.x;
        float uf = uu - floorf(uu);
        float u = uf * (float)A_RESV;                 // in [0,50)
        float v = clamp01(vv) * (float)(A_RESV - 1);
        float x0f = floorf(u), y0f = floorf(v);
        int x0 = (int)x0f;
        int x1 = x0 + 1; if (x1 == A_RESV) x1 = 0;
        int y0 = (int)y0f;
        int y1 = min(y0 + 1, A_RESV - 1);
        float ur = u - x0f, vr = v - y0f;
        hw00 = (1.0f - ur) * (1.0f - vr); hw10 = ur * (1.0f - vr);
        hw01 = (1.0f - ur) * vr;          hw11 = ur * vr;
        oH0 = (y0 * A_RESV + x0) * 8;
        oH1 = (y0 * A_RESV + x1) * 8;
        oH2 = (y1 * A_RESV + x0) * 8;
        oH3 = (y1 * A_RESV + x1) * 8;
    }
    int oD0, oD1, oD2, oD3;  float dw00, dw10, dw01, dw11;
    {
        float uu = p45v.y, vv = p45v.x;
        float uf = uu - floorf(uu);
        float u = uf * (float)A_RESV;
        float v = clamp01(vv) * (float)(A_RESV - 1);
        float x0f = floorf(u), y0f = floorf(v);
        int x0 = (int)x0f;
        int x1 = x0 + 1; if (x1 == A_RESV) x1 = 0;
        int y0 = (int)y0f;
        int y1 = min(y0 + 1, A_RESV - 1);
        float ur = u - x0f, vr = v - y0f;
        dw00 = (1.0f - ur) * (1.0f - vr); dw10 = ur * (1.0f - vr);
        dw01 = (1.0f - ur) * vr;          dw11 = ur * vr;
        oD0 = (y0 * A_RESV + x0) * 8;
        oD1 = (y0 * A_RESV + x1) * 8;
        oD2 = (y1 * A_RESV + x0) * 8;
        oD3 = (y1 * A_RESV + x1) * 8;
    }

    // ---- 4. blob -> LDS (own-wave copy; frees blob regs before texels) ----
    {
        uint4* dst = (uint4*)wl;
        dst[lane]       = wc0;
        dst[lane + 64]  = wc1;
        dst[lane + 128] = wc2;
        dst[lane + 192] = wc3;
        dst[lane + 256] = wc4;
        dst[lane + 320] = wc5;
        dst[lane + 384] = wc6;
        if (lane < 472 - 448) dst[lane + 448] = wc7;
    }

    // ---- 5. issue ALL 12 texel loads (16 B each) ----
    half8 gU0, gU1, gU2, gU3, gH0, gH1, gH2, gH3, gD0, gD1, gD2, gD3;
    float4 sU0, sU1, sU2, sU3, sH0, sH1, sH2, sH3, sD0, sD1, sD2, sD3;
    float4 rU0, rU1, rU2, rU3, rH0, rH1, rH2, rH3, rD0, rD1, rD2, rD3;
    if constexpr (F16P) {
        const _Float16* up = (const _Float16*)u_tex;
        const _Float16* hp = (const _Float16*)h_tex;
        const _Float16* dp = (const _Float16*)d_tex;
        gU0 = *(const half8*)(up + oU0);
        gU1 = *(const half8*)(up + oU1);
        gU2 = *(const half8*)(up + oU2);
        gU3 = *(const half8*)(up + oU3);
        gH0 = *(const half8*)(hp + oH0);
        gH1 = *(const half8*)(hp + oH1);
        gH2 = *(const half8*)(hp + oH2);
        gH3 = *(const half8*)(hp + oH3);
        gD0 = *(const half8*)(dp + oD0);
        gD1 = *(const half8*)(dp + oD1);
        gD2 = *(const half8*)(dp + oD2);
        gD3 = *(const half8*)(dp + oD3);
    } else {
        const float* up = (const float*)u_tex;
        const float* hp = (const float*)h_tex;
        const float* dp = (const float*)d_tex;
        sU0 = *(const float4*)(up + oU0); rU0 = *(const float4*)(up + oU0 + 4);
        sU1 = *(const float4*)(up + oU1); rU1 = *(const float4*)(up + oU1 + 4);
        sU2 = *(const float4*)(up + oU2); rU2 = *(const float4*)(up + oU2 + 4);
        sU3 = *(const float4*)(up + oU3); rU3 = *(const float4*)(up + oU3 + 4);
        sH0 = *(const float4*)(hp + oH0); rH0 = *(const float4*)(hp + oH0 + 4);
        sH1 = *(const float4*)(hp + oH1); rH1 = *(const float4*)(hp + oH1 + 4);
        sH2 = *(const float4*)(hp + oH2); rH2 = *(const float4*)(hp + oH2 + 4);
        sH3 = *(const float4*)(hp + oH3); rH3 = *(const float4*)(hp + oH3 + 4);
        sD0 = *(const float4*)(dp + oD0); rD0 = *(const float4*)(dp + oD0 + 4);
        sD1 = *(const float4*)(dp + oD1); rD1 = *(const float4*)(dp + oD1 + 4);
        sD2 = *(const float4*)(dp + oD2); rD2 = *(const float4*)(dp + oD2 + 4);
        sD3 = *(const float4*)(dp + oD3); rD3 = *(const float4*)(dp + oD3 + 4);
    }
    __builtin_amdgcn_sched_barrier(0);

    // ---- 6. weighted sums, all 8 channels (exact per-channel FMA order) ----
    float fU[8], fH[8], fD[8];
    if constexpr (F16P) {
#pragma unroll
        for (int i = 0; i < 8; ++i) {
            float r = (float)gU0[i] * uw00;
            r = fmaf((float)gU1[i], uw10, r);
            r = fmaf((float)gU2[i], uw01, r);
            r = fmaf((float)gU3[i], uw11, r);
            fU[i] = r;
        }
#pragma unroll
        for (int i = 0; i < 8; ++i) {
            float r = (float)gH0[i] * hw00;
            r = fmaf((float)gH1[i], hw10, r);
            r = fmaf((float)gH2[i], hw01, r);
            r = fmaf((float)gH3[i], hw11, r);
            fH[i] = r;
        }
#pragma unroll
        for (int i = 0; i < 8; ++i) {
            float r = (float)gD0[i] * dw00;
            r = fmaf((float)gD1[i], dw10, r);
            r = fmaf((float)gD2[i], dw01, r);
            r = fmaf((float)gD3[i], dw11, r);
            fD[i] = r;
        }
    } else {
        const float* a;
        const float* b;
        const float* c;
        const float* d;
#pragma unroll
        for (int i = 0; i < 8; ++i) {
            a = i < 4 ? (const float*)&sU0 : (const float*)&rU0;
            b = i < 4 ? (const float*)&sU1 : (const float*)&rU1;
            c = i < 4 ? (const float*)&sU2 : (const float*)&rU2;
            d = i < 4 ? (const float*)&sU3 : (const float*)&rU3;
            int k = i & 3;
            float r = a[k] * uw00;
            r = fmaf(b[k], uw10, r);
            r = fmaf(c[k], uw01, r);
            r = fmaf(d[k], uw11, r);
            fU[i] = r;
        }
#pragma unroll
        for (int i = 0; i < 8; ++i) {
            a = i < 4 ? (const float*)&sH0 : (const float*)&rH0;
            b = i < 4 ? (const float*)&sH1 : (const float*)&rH1;
            c = i < 4 ? (const float*)&sH2 : (const float*)&rH2;
            d = i < 4 ? (const float*)&sH3 : (const float*)&rH3;
            int k = i & 3;
            float r = a[k] * hw00;
            r = fmaf(b[k], hw10, r);
            r = fmaf(c[k], hw01, r);
            r = fmaf(d[k], hw11, r);
            fH[i] = r;
        }
#pragma unroll
        for (int i = 0; i < 8; ++i) {
            a = i < 4 ? (const float*)&sD0 : (const float*)&rD0;
            b = i < 4 ? (const float*)&sD1 : (const float*)&rD1;
            c = i < 4 ? (const float*)&sD2 : (const float*)&rD2;
            d = i < 4 ? (const float*)&sD3 : (const float*)&rD3;
            int k = i & 3;
            float r = a[k] * dw00;
            r = fmaf(b[k], dw10, r);
            r = fmaf(c[k], dw01, r);
            r = fmaf(d[k], dw11, r);
            fD[i] = r;
        }
    }

    // ---- 7. feat -> f16 -> LDS (row = my point) ----
    {
        _Float16* row = fl + tid * 28;
        half8 hU, hH, hD;
#pragma unroll
        for (int i = 0; i < 8; ++i) {
            hU[i] = (_Float16)fU[i];
            hH[i] = (_Float16)fH[i];
            hD[i] = (_Float16)fD[i];
        }
        *(half8*)(row)      = hU;   // ch 0-7
        *(half8*)(row + 8)  = hH;   // ch 8-15
        *(half8*)(row + 16) = hD;   // ch 16-23
    }
    // wave-local handoff: my blob copy + my wave's feat rows are retired;
    // no block barrier anywhere (same-value blob races across waves benign)
    asm volatile("s_waitcnt lgkmcnt(0)" ::: "memory");
    __builtin_amdgcn_sched_barrier(0);

    // ---- 8. MLP: wave owns 64 points, j-tiles {0..3} ----
    floatx4 zf; zf[0] = 0.f; zf[1] = 0.f; zf[2] = 0.f; zf[3] = 0.f;
    const _Float16* wb = fl + (size_t)wv * 64 * 28;
    const _Float16* w0l = wl + W0OFF;
    const _Float16* w1l = wl + W1OFF;
    const _Float16* w2l = wl + W2OFF;
    const _Float16* w3l = wl + W3OFF;

    half4 b0[4], b1[4];
#pragma unroll
    for (int j = 0; j < 4; ++j) {
        const _Float16* r = wb + (size_t)(j * 16 + c15) * 28;
        b0[j] = *(const half4*)(r + q * 4);
        b1[j] = (q < 2) ? *(const half4*)(r + 16 + q * 4) : zero4();
    }

    floatx4 cc[2][4];
    // layer 0 (K=24: k-half1 zero for q>=2 on both operands; W0 stride 28)
#pragma unroll
    for (int m = 0; m < 2; ++m) {
        half4 a0 = *(const half4*)(w0l + (size_t)(16 * m + c15) * 28 + q * 4);
        half4 a1 = (q < 2) ? *(const half4*)(w0l + (size_t)(16 * m + c15) * 28 + 16 + q * 4) : zero4();
#pragma unroll
        for (int j = 0; j < 4; ++j)
            cc[m][j] = mfma16(a1, b1[j], mfma16(a0, b0[j], zf));
    }
#pragma unroll
    for (int j = 0; j < 4; ++j) {
#pragma unroll
        for (int e = 0; e < 4; ++e) {
            b0[j][e] = (_Float16)cc[0][j][e];
            b1[j][e] = (_Float16)cc[1][j][e];
        }
        b0[j] = relu4(b0[j]);
        b1[j] = relu4(b1[j]);
    }

    // layer 1
#pragma unroll
    for (int m = 0; m < 2; ++m) {
        half4 a0 = *(const half4*)(w1l + (size_t)(16 * m + c15) * 36 + q * 4);
        half4 a1 = *(const half4*)(w1l + (size_t)(16 * m + c15) * 36 + 16 + q * 4);
#pragma unroll
        for (int j = 0; j < 4; ++j)
            cc[m][j] = mfma16(a1, b1[j], mfma16(a0, b0[j], zf));
    }
#pragma unroll
    for (int j = 0; j < 4; ++j) {
#pragma unroll
        for (int e = 0; e < 4; ++e) {
            b0[j][e] = (_Float16)cc[0][j][e];
            b1[j][e] = (_Float16)cc[1][j][e];
        }
        b0[j] = relu4(b0[j]);
        b1[j] = relu4(b1[j]);
    }

    // layer 2
#pragma unroll
    for (int m = 0; m < 2; ++m) {
        half4 a0 = *(const half4*)(w2l + (size_t)(16 * m + c15) * 36 + q * 4);
        half4 a1 = *(const half4*)(w2l + (size_t)(16 * m + c15) * 36 + 16 + q * 4);
#pragma unroll
        for (int j = 0; j < 4; ++j)
            cc[m][j] = mfma16(a1, b1[j], mfma16(a0, b0[j], zf));
    }
#pragma unroll
    for (int j = 0; j < 4; ++j) {
#pragma unroll
        for (int e = 0; e < 4; ++e) {
            b0[j][e] = (_Float16)cc[0][j][e];
            b1[j][e] = (_Float16)cc[1][j][e];
        }
        b0[j] = relu4(b0[j]);
        b1[j] = relu4(b1[j]);
    }

    // layer 3 (rows 0-2 valid; w3l rows 3-15 zero)
    floatx4 c3[4];
    {
        half4 a0 = *(const half4*)(w3l + (size_t)c15 * 36 + q * 4);
        half4 a1 = *(const half4*)(w3l + (size_t)c15 * 36 + 16 + q * 4);
#pragma unroll
        for (int j = 0; j < 4; ++j)
            c3[j] = mfma16(a1, b1[j], mfma16(a0, b0[j], zf));
    }

    if (lane < 16) {
        const size_t base = (size_t)blockIdx.x * 512 + (size_t)wv * 64;
#pragma unroll
        for (int j = 0; j < 4; ++j) {
            size_t p = base + (size_t)j * 16 + lane;
            float* o = out + p * 3;
            o[0] = c3[j][0];
            o[1] = c3[j][1];
            o[2] = c3[j][2];
        }
    }
}

extern "C" void kernel_launch(void* const* d_in, const int* in_sizes, int n_in,
                              void* d_out, int out_size, void* d_ws, size_t ws_size,
                              hipStream_t stream) {
    const float* x       = (const float*)d_in[0];
    const float* u_plane = (const float*)d_in[1];
    const float* h_plane = (const float*)d_in[2];
    const float* d_plane = (const float*)d_in[3];
    const float* W0      = (const float*)d_in[4];
    const float* W1      = (const float*)d_in[5];
    const float* W2      = (const float*)d_in[6];
    const float* W3      = (const float*)d_in[7];
    float* out = (float*)d_out;
    _Float16* wsw = (_Float16*)d_ws;

    int n = in_sizes[0] / 6;          // 2^21
    int grid = n / 512;               // 512 points per block, 1 thread/point

    const size_t need = ((size_t)WOFF + WTOT) * 2;
    if (ws_size >= need) {
        pconv_kernel<<<648, 256, 0, stream>>>(u_plane, h_plane, d_plane,
                                              W0, W1, W2, W3, wsw);
        tpmlp_kernel<true><<<grid, 512, 0, stream>>>(
            x, (const void*)wsw, (const void*)(wsw + UHALVES),
            (const void*)(wsw + UHALVES + AHALVES), wsw + WOFF, out);
    } else {
        wprep_kernel<<<1, 256, 0, stream>>>(W0, W1, W2, W3, wsw);
        tpmlp_kernel<false><<<grid, 512, 0, stream>>>(
            x, (const void*)u_plane, (const void*)h_plane, (const void*)d_plane,
            wsw, out);
    }
}

// Round 15
// 75.524 us; speedup vs baseline: 1.0354x; 1.0354x over previous
//
#include <hip/hip_runtime.h>

typedef _Float16 half4 __attribute__((ext_vector_type(4)));
typedef _Float16 half8 __attribute__((ext_vector_type(8)));
typedef float floatx4 __attribute__((ext_vector_type(4)));

#define U_RESV 400
#define A_RESV 50

#define UHALVES (U_RESV * U_RESV * 8)   // 1,280,000
#define AHALVES (A_RESV * A_RESV * 8)   // 20,000
#define WOFF    (UHALVES + 2 * AHALVES) // weights offset (halves)
// W0 32x28 (cols>=24 zero) | W1 32x36 | W2 32x36 | W3 16x36 (rows>=3 zero)
#define W0OFF   0
#define W1OFF   896
#define W2OFF   2048
#define W3OFF   3200
#define WTOT    3776                    // halves; 7552 B = 472 x 16 B

__device__ __forceinline__ float clamp01(float x) { return fminf(fmaxf(x, 0.0f), 1.0f); }

__device__ __forceinline__ floatx4 mfma16(half4 a, half4 b, floatx4 c) {
    return __builtin_amdgcn_mfma_f32_16x16x16f16(a, b, c, 0, 0, 0);
}
__device__ __forceinline__ half4 zero4() {
    half4 h; h[0] = h[1] = h[2] = h[3] = (_Float16)0.f; return h;
}
__device__ __forceinline__ half4 relu4(half4 v) {
#if __has_builtin(__builtin_elementwise_max)
    return __builtin_elementwise_max(v, zero4());
#else
    half4 r;
#pragma unroll
    for (int i = 0; i < 4; ++i) r[i] = v[i] > (_Float16)0.f ? v[i] : (_Float16)0.f;
    return r;
#endif
}

__device__ __forceinline__ void cvt_chunk(const float* __restrict__ src,
                                          _Float16* __restrict__ dst, int i) {
    float4 a = *(const float4*)(src + (size_t)i * 8);
    float4 b = *(const float4*)(src + (size_t)i * 8 + 4);
    half8 h;
    h[0] = (_Float16)a.x; h[1] = (_Float16)a.y; h[2] = (_Float16)a.z; h[3] = (_Float16)a.w;
    h[4] = (_Float16)b.x; h[5] = (_Float16)b.y; h[6] = (_Float16)b.z; h[7] = (_Float16)b.w;
    *(half8*)(dst + (size_t)i * 8) = h;
}

__device__ __forceinline__ void wblob_fill(const float* __restrict__ W0,
                                           const float* __restrict__ W1,
                                           const float* __restrict__ W2,
                                           const float* __restrict__ W3,
                                           _Float16* __restrict__ w, int tid, int nthr) {
    for (int i = tid; i < WTOT; i += nthr) {
        float v;
        if (i < W1OFF) {
            int r = i / 28, c = i - r * 28;
            v = (c < 24) ? W0[r * 24 + c] : 0.f;
        } else if (i < W2OFF) {
            int j = i - W1OFF, r = j / 36, c = j - r * 36;
            v = (c < 32) ? W1[r * 32 + c] : 0.f;
        } else if (i < W3OFF) {
            int j = i - W2OFF, r = j / 36, c = j - r * 36;
            v = (c < 32) ? W2[r * 32 + c] : 0.f;
        } else {
            int j = i - W3OFF, r = j / 36, c = j - r * 36;
            v = (r < 3 && c < 32) ? W3[r * 32 + c] : 0.f;
        }
        w[i] = (_Float16)v;
    }
}

// ---- prep kernels ----
__global__ __launch_bounds__(256) void pconv_kernel(
    const float* __restrict__ u_plane, const float* __restrict__ h_plane,
    const float* __restrict__ d_plane, const float* __restrict__ W0,
    const float* __restrict__ W1, const float* __restrict__ W2,
    const float* __restrict__ W3, _Float16* __restrict__ dst) {
    const int gid = blockIdx.x * 256 + threadIdx.x;
    const int gsz = gridDim.x * 256;
    for (int i = gid; i < UHALVES / 8; i += gsz) cvt_chunk(u_plane, dst, i);
    for (int i = gid; i < AHALVES / 8; i += gsz) cvt_chunk(h_plane, dst + UHALVES, i);
    for (int i = gid; i < AHALVES / 8; i += gsz) cvt_chunk(d_plane, dst + UHALVES + AHALVES, i);
    if (blockIdx.x == 0) wblob_fill(W0, W1, W2, W3, dst + WOFF, threadIdx.x, 256);
}

__global__ __launch_bounds__(256) void wprep_kernel(
    const float* __restrict__ W0, const float* __restrict__ W1,
    const float* __restrict__ W2, const float* __restrict__ W3,
    _Float16* __restrict__ wdst) {
    wblob_fill(W0, W1, W2, W3, wdst, threadIdx.x, 256);
}

// Bilerp address+weight bundle (arithmetic identical to R5..R14)
struct GA { int o0, o1, o2, o3; float w00, w10, w01, w11; };

__device__ __forceinline__ GA mkU(float ux, float uy) {
    GA g;
    float u = clamp01(ux) * (float)(U_RESV - 1);
    float v = clamp01(uy) * (float)(U_RESV - 1);
    float x0f = floorf(u), y0f = floorf(v);
    int x0 = (int)x0f, y0 = (int)y0f;
    int x1 = min(x0 + 1, U_RESV - 1), y1 = min(y0 + 1, U_RESV - 1);
    float ur = u - x0f, vr = v - y0f;
    g.w00 = (1.0f - ur) * (1.0f - vr); g.w10 = ur * (1.0f - vr);
    g.w01 = (1.0f - ur) * vr;          g.w11 = ur * vr;
    g.o0 = (y0 * U_RESV + x0) * 8;
    g.o1 = (y0 * U_RESV + x1) * 8;
    g.o2 = (y1 * U_RESV + x0) * 8;
    g.o3 = (y1 * U_RESV + x1) * 8;
    return g;
}
__device__ __forceinline__ GA mkA(float uu, float vv) {
    GA g;
    float uf = uu - floorf(uu);
    float u = uf * (float)A_RESV;                 // in [0,50)
    float v = clamp01(vv) * (float)(A_RESV - 1);
    float x0f = floorf(u), y0f = floorf(v);
    int x0 = (int)x0f;
    int x1 = x0 + 1; if (x1 == A_RESV) x1 = 0;
    int y0 = (int)y0f;
    int y1 = min(y0 + 1, A_RESV - 1);
    float ur = u - x0f, vr = v - y0f;
    g.w00 = (1.0f - ur) * (1.0f - vr); g.w10 = ur * (1.0f - vr);
    g.w01 = (1.0f - ur) * vr;          g.w11 = ur * vr;
    g.o0 = (y0 * A_RESV + x0) * 8;
    g.o1 = (y0 * A_RESV + x1) * 8;
    g.o2 = (y1 * A_RESV + x0) * 8;
    g.o3 = (y1 * A_RESV + x1) * 8;
    return g;
}

__device__ __forceinline__ void blend8(half8 a, half8 b, half8 c, half8 d,
                                       const GA& g, float* f) {
#pragma unroll
    for (int i = 0; i < 8; ++i) {
        float r = (float)a[i] * g.w00;
        r = fmaf((float)b[i], g.w10, r);
        r = fmaf((float)c[i], g.w01, r);
        r = fmaf((float)d[i], g.w11, r);
        f[i] = r;
    }
}

// R15: grid-stride software pipeline. Each thread owns K points; batch it+1's
// texel loads are issued BEFORE batch it is consumed (x prefetched 2 deep), so
// gather latency hides under bilerp+MLP compute. Weights staged once, barrier
// OUTSIDE the hot loop. Per-point arithmetic byte-identical to R13.
// MFMA maps (verified R4..R14, 16x16x16 f16):
//   A: lane 16q+c holds A[row=c][k=4q+e];  B: lane 16q+c holds B[k=4q+e][col=c]
//   D: lane 16q+c reg r holds D[row=4q+r][col=c]
// Chain identity: D reg r == next-layer B elem e. Wave owns 64 pts/iter.

template <int K>
__global__ __launch_bounds__(256, 2) void tpmlp_pipe(
    const float* __restrict__ x,
    const _Float16* __restrict__ up,
    const _Float16* __restrict__ hp,
    const _Float16* __restrict__ dp,
    const _Float16* __restrict__ wsw,
    float* __restrict__ out) {
    const int tid  = threadIdx.x;
    const int lane = tid & 63;
    const int wv   = tid >> 6;
    const int q    = lane >> 4;
    const int c15  = lane & 15;

    __shared__ __align__(16) _Float16 fl[256 * 28];   // 14.3 KB (per-wave slices)
    __shared__ __align__(16) _Float16 wl[WTOT];       // 7.5 KB

    // ---- stage weights once; only barrier in the kernel ----
    {
        const uint4* src = (const uint4*)wsw;
        uint4 a = src[tid];
        uint4 b;
        if (tid < 472 - 256) b = src[256 + tid];
        uint4* dst = (uint4*)wl;
        dst[tid] = a;
        if (tid < 472 - 256) dst[256 + tid] = b;
    }
    __syncthreads();

    const _Float16* wb  = fl + (size_t)wv * 64 * 28;
    const _Float16* w0l = wl + W0OFF;
    const _Float16* w1l = wl + W1OFF;
    const _Float16* w2l = wl + W2OFF;
    const _Float16* w3l = wl + W3OFF;
    const size_t blkbase = (size_t)blockIdx.x * (256 * K);

    auto xload = [&](int it, float2& a, float2& b, float2& c) {
        const float2* p = (const float2*)(x + (blkbase + (size_t)it * 256 + tid) * 6);
        a = p[0]; b = p[1]; c = p[2];
    };

    // ---- prologue: x depth-2, texel batch 0 in flight ----
    float2 c01, c23, c45;          // x of batch it (consumed into addr already for it=0)
    float2 n01, n23, n45;          // x of batch it+1
    xload(0, c01, c23, c45);
    if (K > 1) xload(1, n01, n23, n45);

    GA gU = mkU(c01.x, c01.y);
    GA gH = mkA(c23.y, c23.x);
    GA gD = mkA(c45.y, c45.x);
    half8 tU0 = *(const half8*)(up + gU.o0);
    half8 tU1 = *(const half8*)(up + gU.o1);
    half8 tU2 = *(const half8*)(up + gU.o2);
    half8 tU3 = *(const half8*)(up + gU.o3);
    half8 tH0 = *(const half8*)(hp + gH.o0);
    half8 tH1 = *(const half8*)(hp + gH.o1);
    half8 tH2 = *(const half8*)(hp + gH.o2);
    half8 tH3 = *(const half8*)(hp + gH.o3);
    half8 tD0 = *(const half8*)(dp + gD.o0);
    half8 tD1 = *(const half8*)(dp + gD.o1);
    half8 tD2 = *(const half8*)(dp + gD.o2);
    half8 tD3 = *(const half8*)(dp + gD.o3);
    __builtin_amdgcn_sched_barrier(0);

#pragma unroll
    for (int it = 0; it < K; ++it) {
        // ---- prefetch batch it+1 (issue before consuming batch it) ----
        GA pU, pH, pD;
        half8 mU0, mU1, mU2, mU3, mH0, mH1, mH2, mH3, mD0, mD1, mD2, mD3;
        float2 f01 = n01, f23 = n23, f45 = n45;
        if (it + 2 < K) xload(it + 2, n01, n23, n45);
        if (it + 1 < K) {
            pU = mkU(f01.x, f01.y);
            pH = mkA(f23.y, f23.x);
            pD = mkA(f45.y, f45.x);
            mU0 = *(const half8*)(up + pU.o0);
            mU1 = *(const half8*)(up + pU.o1);
            mU2 = *(const half8*)(up + pU.o2);
            mU3 = *(const half8*)(up + pU.o3);
            mH0 = *(const half8*)(hp + pH.o0);
            mH1 = *(const half8*)(hp + pH.o1);
            mH2 = *(const half8*)(hp + pH.o2);
            mH3 = *(const half8*)(hp + pH.o3);
            mD0 = *(const half8*)(dp + pD.o0);
            mD1 = *(const half8*)(dp + pD.o1);
            mD2 = *(const half8*)(dp + pD.o2);
            mD3 = *(const half8*)(dp + pD.o3);
            __builtin_amdgcn_sched_barrier(0);
        }

        // ---- consume batch it: bilerp (exact verified FMA order) ----
        float fU[8], fH[8], fD[8];
        blend8(tU0, tU1, tU2, tU3, gU, fU);
        blend8(tH0, tH1, tH2, tH3, gH, fH);
        blend8(tD0, tD1, tD2, tD3, gD, fD);

        // feat -> f16 -> LDS (row = my point)
        {
            _Float16* row = fl + tid * 28;
            half8 hU, hH, hD;
#pragma unroll
            for (int i = 0; i < 8; ++i) {
                hU[i] = (_Float16)fU[i];
                hH[i] = (_Float16)fH[i];
                hD[i] = (_Float16)fD[i];
            }
            *(half8*)(row)      = hU;
            *(half8*)(row + 8)  = hH;
            *(half8*)(row + 16) = hD;
        }
        // wave-local handoff (same-wave lockstep; verified R8..R14)
        asm volatile("s_waitcnt lgkmcnt(0)" ::: "memory");
        __builtin_amdgcn_sched_barrier(0);

        // ---- MLP: wave owns 64 points, j-tiles {0..3} ----
        floatx4 zf; zf[0] = 0.f; zf[1] = 0.f; zf[2] = 0.f; zf[3] = 0.f;
        half4 b0[4], b1[4];
#pragma unroll
        for (int j = 0; j < 4; ++j) {
            const _Float16* r = wb + (size_t)(j * 16 + c15) * 28;
            b0[j] = *(const half4*)(r + q * 4);
            b1[j] = (q < 2) ? *(const half4*)(r + 16 + q * 4) : zero4();
        }

        floatx4 cc[2][4];
#pragma unroll
        for (int m = 0; m < 2; ++m) {
            half4 a0 = *(const half4*)(w0l + (size_t)(16 * m + c15) * 28 + q * 4);
            half4 a1 = (q < 2) ? *(const half4*)(w0l + (size_t)(16 * m + c15) * 28 + 16 + q * 4) : zero4();
#pragma unroll
            for (int j = 0; j < 4; ++j)
                cc[m][j] = mfma16(a1, b1[j], mfma16(a0, b0[j], zf));
        }
#pragma unroll
        for (int j = 0; j < 4; ++j) {
#pragma unroll
            for (int e = 0; e < 4; ++e) {
                b0[j][e] = (_Float16)cc[0][j][e];
                b1[j][e] = (_Float16)cc[1][j][e];
            }
            b0[j] = relu4(b0[j]);
            b1[j] = relu4(b1[j]);
        }

#pragma unroll
        for (int m = 0; m < 2; ++m) {
            half4 a0 = *(const half4*)(w1l + (size_t)(16 * m + c15) * 36 + q * 4);
            half4 a1 = *(const half4*)(w1l + (size_t)(16 * m + c15) * 36 + 16 + q * 4);
#pragma unroll
            for (int j = 0; j < 4; ++j)
                cc[m][j] = mfma16(a1, b1[j], mfma16(a0, b0[j], zf));
        }
#pragma unroll
        for (int j = 0; j < 4; ++j) {
#pragma unroll
            for (int e = 0; e < 4; ++e) {
                b0[j][e] = (_Float16)cc[0][j][e];
                b1[j][e] = (_Float16)cc[1][j][e];
            }
            b0[j] = relu4(b0[j]);
            b1[j] = relu4(b1[j]);
        }

#pragma unroll
        for (int m = 0; m < 2; ++m) {
            half4 a0 = *(const half4*)(w2l + (size_t)(16 * m + c15) * 36 + q * 4);
            half4 a1 = *(const half4*)(w2l + (size_t)(16 * m + c15) * 36 + 16 + q * 4);
#pragma unroll
            for (int j = 0; j < 4; ++j)
                cc[m][j] = mfma16(a1, b1[j], mfma16(a0, b0[j], zf));
        }
#pragma unroll
        for (int j = 0; j < 4; ++j) {
#pragma unroll
            for (int e = 0; e < 4; ++e) {
                b0[j][e] = (_Float16)cc[0][j][e];
                b1[j][e] = (_Float16)cc[1][j][e];
            }
            b0[j] = relu4(b0[j]);
            b1[j] = relu4(b1[j]);
        }

        floatx4 c3[4];
        {
            half4 a0 = *(const half4*)(w3l + (size_t)c15 * 36 + q * 4);
            half4 a1 = *(const half4*)(w3l + (size_t)c15 * 36 + 16 + q * 4);
#pragma unroll
            for (int j = 0; j < 4; ++j)
                c3[j] = mfma16(a1, b1[j], mfma16(a0, b0[j], zf));
        }

        if (lane < 16) {
            const size_t base = blkbase + (size_t)it * 256 + (size_t)wv * 64;
#pragma unroll
            for (int j = 0; j < 4; ++j) {
                size_t p = base + (size_t)j * 16 + lane;
                float* o = out + p * 3;
                o[0] = c3[j][0];
                o[1] = c3[j][1];
                o[2] = c3[j][2];
            }
        }

        // ---- rotate pipeline state ----
        if (it + 1 < K) {
            gU = pU; gH = pH; gD = pD;
            tU0 = mU0; tU1 = mU1; tU2 = mU2; tU3 = mU3;
            tH0 = mH0; tH1 = mH1; tH2 = mH2; tH3 = mH3;
            tD0 = mD0; tD1 = mD1; tD2 = mD2; tD3 = mD3;
        }
    }
}

// ---- fallback (f32 planes, non-pipelined R13 structure) ----
__global__ __launch_bounds__(512, 2) void tpmlp_f32(
    const float* __restrict__ x,
    const float* __restrict__ up,
    const float* __restrict__ hp,
    const float* __restrict__ dp,
    const _Float16* __restrict__ wsw,
    float* __restrict__ out) {
    const int tid  = threadIdx.x;
    const int lane = tid & 63;
    const int wv   = tid >> 6;
    const int q    = lane >> 4;
    const int c15  = lane & 15;

    __shared__ __align__(16) _Float16 fl[512 * 28];
    __shared__ __align__(16) _Float16 wl[WTOT];

    const size_t P = (size_t)blockIdx.x * 512 + tid;
    const float2* xp = (const float2*)(x + P * 6);
    float2 p01v = xp[0], p23v = xp[1], p45v = xp[2];

    uint4 w_a;
    if (tid < 472) w_a = ((const uint4*)wsw)[tid];

    GA gU = mkU(p01v.x, p01v.y);
    GA gH = mkA(p23v.y, p23v.x);
    GA gD = mkA(p45v.y, p45v.x);

    float4 sU0 = *(const float4*)(up + gU.o0); float4 rU0 = *(const float4*)(up + gU.o0 + 4);
    float4 sU1 = *(const float4*)(up + gU.o1); float4 rU1 = *(const float4*)(up + gU.o1 + 4);
    float4 sU2 = *(const float4*)(up + gU.o2); float4 rU2 = *(const float4*)(up + gU.o2 + 4);
    float4 sU3 = *(const float4*)(up + gU.o3); float4 rU3 = *(const float4*)(up + gU.o3 + 4);
    float4 sH0 = *(const float4*)(hp + gH.o0); float4 rH0 = *(const float4*)(hp + gH.o0 + 4);
    float4 sH1 = *(const float4*)(hp + gH.o1); float4 rH1 = *(const float4*)(hp + gH.o1 + 4);
    float4 sH2 = *(const float4*)(hp + gH.o2); float4 rH2 = *(const float4*)(hp + gH.o2 + 4);
    float4 sH3 = *(const float4*)(hp + gH.o3); float4 rH3 = *(const float4*)(hp + gH.o3 + 4);
    float4 sD0 = *(const float4*)(dp + gD.o0); float4 rD0 = *(const float4*)(dp + gD.o0 + 4);
    float4 sD1 = *(const float4*)(dp + gD.o1); float4 rD1 = *(const float4*)(dp + gD.o1 + 4);
    float4 sD2 = *(const float4*)(dp + gD.o2); float4 rD2 = *(const float4*)(dp + gD.o2 + 4);
    float4 sD3 = *(const float4*)(dp + gD.o3); float4 rD3 = *(const float4*)(dp + gD.o3 + 4);
    __builtin_amdgcn_sched_barrier(0);

    if (tid < 472) ((uint4*)wl)[tid] = w_a;
    asm volatile("s_waitcnt lgkmcnt(0)" ::: "memory");
    __builtin_amdgcn_s_barrier();

    float fU[8], fH[8], fD[8];
#pragma unroll
    for (int i = 0; i < 8; ++i) {
        const float* a = i < 4 ? (const float*)&sU0 : (const float*)&rU0;
        const float* b = i < 4 ? (const float*)&sU1 : (const float*)&rU1;
        const float* c = i < 4 ? (const float*)&sU2 : (const float*)&rU2;
        const float* d = i < 4 ? (const float*)&sU3 : (const float*)&rU3;
        int k = i & 3;
        float r = a[k] * gU.w00;
        r = fmaf(b[k], gU.w10, r);
        r = fmaf(c[k], gU.w01, r);
        r = fmaf(d[k], gU.w11, r);
        fU[i] = r;
    }
#pragma unroll
    for (int i = 0; i < 8; ++i) {
        const float* a = i < 4 ? (const float*)&sH0 : (const float*)&rH0;
        const float* b = i < 4 ? (const float*)&sH1 : (const float*)&rH1;
        const float* c = i < 4 ? (const float*)&sH2 : (const float*)&rH2;
        const float* d = i < 4 ? (const float*)&sH3 : (const float*)&rH3;
        int k = i & 3;
        float r = a[k] * gH.w00;
        r = fmaf(b[k], gH.w10, r);
        r = fmaf(c[k], gH.w01, r);
        r = fmaf(d[k], gH.w11, r);
        fH[i] = r;
    }
#pragma unroll
    for (int i = 0; i < 8; ++i) {
        const float* a = i < 4 ? (const float*)&sD0 : (const float*)&rD0;
        const float* b = i < 4 ? (const float*)&sD1 : (const float*)&rD1;
        const float* c = i < 4 ? (const float*)&sD2 : (const float*)&rD2;
        const float* d = i < 4 ? (const float*)&sD3 : (const float*)&rD3;
        int k = i & 3;
        float r = a[k] * gD.w00;
        r = fmaf(b[k], gD.w10, r);
        r = fmaf(c[k], gD.w01, r);
        r = fmaf(d[k], gD.w11, r);
        fD[i] = r;
    }

    {
        _Float16* row = fl + tid * 28;
        half8 hU, hH, hD;
#pragma unroll
        for (int i = 0; i < 8; ++i) {
            hU[i] = (_Float16)fU[i];
            hH[i] = (_Float16)fH[i];
            hD[i] = (_Float16)fD[i];
        }
        *(half8*)(row)      = hU;
        *(half8*)(row + 8)  = hH;
        *(half8*)(row + 16) = hD;
    }
    asm volatile("s_waitcnt lgkmcnt(0)" ::: "memory");
    __builtin_amdgcn_sched_barrier(0);

    floatx4 zf; zf[0] = 0.f; zf[1] = 0.f; zf[2] = 0.f; zf[3] = 0.f;
    const _Float16* wb = fl + (size_t)wv * 64 * 28;
    const _Float16* w0l = wl + W0OFF;
    const _Float16* w1l = wl + W1OFF;
    const _Float16* w2l = wl + W2OFF;
    const _Float16* w3l = wl + W3OFF;

    half4 b0[4], b1[4];
#pragma unroll
    for (int j = 0; j < 4; ++j) {
        const _Float16* r = wb + (size_t)(j * 16 + c15) * 28;
        b0[j] = *(const half4*)(r + q * 4);
        b1[j] = (q < 2) ? *(const half4*)(r + 16 + q * 4) : zero4();
    }

    floatx4 cc[2][4];
#pragma unroll
    for (int m = 0; m < 2; ++m) {
        half4 a0 = *(const half4*)(w0l + (size_t)(16 * m + c15) * 28 + q * 4);
        half4 a1 = (q < 2) ? *(const half4*)(w0l + (size_t)(16 * m + c15) * 28 + 16 + q * 4) : zero4();
#pragma unroll
        for (int j = 0; j < 4; ++j)
            cc[m][j] = mfma16(a1, b1[j], mfma16(a0, b0[j], zf));
    }
#pragma unroll
    for (int j = 0; j < 4; ++j) {
#pragma unroll
        for (int e = 0; e < 4; ++e) {
            b0[j][e] = (_Float16)cc[0][j][e];
            b1[j][e] = (_Float16)cc[1][j][e];
        }
        b0[j] = relu4(b0[j]);
        b1[j] = relu4(b1[j]);
    }
#pragma unroll
    for (int m = 0; m < 2; ++m) {
        half4 a0 = *(const half4*)(w1l + (size_t)(16 * m + c15) * 36 + q * 4);
        half4 a1 = *(const half4*)(w1l + (size_t)(16 * m + c15) * 36 + 16 + q * 4);
#pragma unroll
        for (int j = 0; j < 4; ++j)
            cc[m][j] = mfma16(a1, b1[j], mfma16(a0, b0[j], zf));
    }
#pragma unroll
    for (int j = 0; j < 4; ++j) {
#pragma unroll
        for (int e = 0; e < 4; ++e) {
            b0[j][e] = (_Float16)cc[0][j][e];
            b1[j][e] = (_Float16)cc[1][j][e];
        }
        b0[j] = relu4(b0[j]);
        b1[j] = relu4(b1[j]);
    }
#pragma unroll
    for (int m = 0; m < 2; ++m) {
        half4 a0 = *(const half4*)(w2l + (size_t)(16 * m + c15) * 36 + q * 4);
        half4 a1 = *(const half4*)(w2l + (size_t)(16 * m + c15) * 36 + 16 + q * 4);
#pragma unroll
        for (int j = 0; j < 4; ++j)
            cc[m][j] = mfma16(a1, b1[j], mfma16(a0, b0[j], zf));
    }
#pragma unroll
    for (int j = 0; j < 4; ++j) {
#pragma unroll
        for (int e = 0; e < 4; ++e) {
            b0[j][e] = (_Float16)cc[0][j][e];
            b1[j][e] = (_Float16)cc[1][j][e];
        }
        b0[j] = relu4(b0[j]);
        b1[j] = relu4(b1[j]);
    }

    floatx4 c3[4];
    {
        half4 a0 = *(const half4*)(w3l + (size_t)c15 * 36 + q * 4);
        half4 a1 = *(const half4*)(w3l + (size_t)c15 * 36 + 16 + q * 4);
#pragma unroll
        for (int j = 0; j < 4; ++j)
            c3[j] = mfma16(a1, b1[j], mfma16(a0, b0[j], zf));
    }

    if (lane < 16) {
        const size_t base = (size_t)blockIdx.x * 512 + (size_t)wv * 64;
#pragma unroll
        for (int j = 0; j < 4; ++j) {
            size_t p = base + (size_t)j * 16 + lane;
            float* o = out + p * 3;
            o[0] = c3[j][0];
            o[1] = c3[j][1];
            o[2] = c3[j][2];
        }
    }
}

extern "C" void kernel_launch(void* const* d_in, const int* in_sizes, int n_in,
                              void* d_out, int out_size, void* d_ws, size_t ws_size,
                              hipStream_t stream) {
    const float* x       = (const float*)d_in[0];
    const float* u_plane = (const float*)d_in[1];
    const float* h_plane = (const float*)d_in[2];
    const float* d_plane = (const float*)d_in[3];
    const float* W0      = (const float*)d_in[4];
    const float* W1      = (const float*)d_in[5];
    const float* W2      = (const float*)d_in[6];
    const float* W3      = (const float*)d_in[7];
    float* out = (float*)d_out;
    _Float16* wsw = (_Float16*)d_ws;

    int n = in_sizes[0] / 6;          // 2^21
    constexpr int K = 8;

    const size_t need = ((size_t)WOFF + WTOT) * 2;
    if (ws_size >= need) {
        pconv_kernel<<<648, 256, 0, stream>>>(u_plane, h_plane, d_plane,
                                              W0, W1, W2, W3, wsw);
        int grid = n / (256 * K);     // 1024 blocks
        tpmlp_pipe<K><<<grid, 256, 0, stream>>>(
            x, wsw, wsw + UHALVES, wsw + UHALVES + AHALVES, wsw + WOFF, out);
    } else {
        wprep_kernel<<<1, 256, 0, stream>>>(W0, W1, W2, W3, wsw);
        tpmlp_f32<<<n / 512, 512, 0, stream>>>(
            x, u_plane, h_plane, d_plane, wsw, out);
    }
}

// Round 16
// 74.442 us; speedup vs baseline: 1.0504x; 1.0145x over previous
//
#include <hip/hip_runtime.h>

typedef _Float16 half4 __attribute__((ext_vector_type(4)));
typedef _Float16 half8 __attribute__((ext_vector_type(8)));
typedef float floatx4 __attribute__((ext_vector_type(4)));

#define U_RESV 400
#define A_RESV 50

#define UHALVES (U_RESV * U_RESV * 8)   // 1,280,000
#define AHALVES (A_RESV * A_RESV * 8)   // 20,000
#define WOFF    (UHALVES + 2 * AHALVES) // weights offset (halves)
// W0 32x28 (cols>=24 zero) | W1 32x36 | W2 32x36 | W3 16x36 (rows>=3 zero)
#define W0OFF   0
#define W1OFF   896
#define W2OFF   2048
#define W3OFF   3200
#define WTOT    3776                    // halves; 7552 B = 472 x 16 B

__device__ __forceinline__ float clamp01(float x) { return fminf(fmaxf(x, 0.0f), 1.0f); }

__device__ __forceinline__ floatx4 mfma16(half4 a, half4 b, floatx4 c) {
    return __builtin_amdgcn_mfma_f32_16x16x16f16(a, b, c, 0, 0, 0);
}
__device__ __forceinline__ half4 zero4() {
    half4 h; h[0] = h[1] = h[2] = h[3] = (_Float16)0.f; return h;
}
__device__ __forceinline__ half4 relu4(half4 v) {
#if __has_builtin(__builtin_elementwise_max)
    return __builtin_elementwise_max(v, zero4());
#else
    half4 r;
#pragma unroll
    for (int i = 0; i < 4; ++i) r[i] = v[i] > (_Float16)0.f ? v[i] : (_Float16)0.f;
    return r;
#endif
}

__device__ __forceinline__ void cvt_chunk(const float* __restrict__ src,
                                          _Float16* __restrict__ dst, int i) {
    float4 a = *(const float4*)(src + (size_t)i * 8);
    float4 b = *(const float4*)(src + (size_t)i * 8 + 4);
    half8 h;
    h[0] = (_Float16)a.x; h[1] = (_Float16)a.y; h[2] = (_Float16)a.z; h[3] = (_Float16)a.w;
    h[4] = (_Float16)b.x; h[5] = (_Float16)b.y; h[6] = (_Float16)b.z; h[7] = (_Float16)b.w;
    *(half8*)(dst + (size_t)i * 8) = h;
}

__device__ __forceinline__ void wblob_fill(const float* __restrict__ W0,
                                           const float* __restrict__ W1,
                                           const float* __restrict__ W2,
                                           const float* __restrict__ W3,
                                           _Float16* __restrict__ w, int tid, int nthr) {
    for (int i = tid; i < WTOT; i += nthr) {
        float v;
        if (i < W1OFF) {
            int r = i / 28, c = i - r * 28;
            v = (c < 24) ? W0[r * 24 + c] : 0.f;
        } else if (i < W2OFF) {
            int j = i - W1OFF, r = j / 36, c = j - r * 36;
            v = (c < 32) ? W1[r * 32 + c] : 0.f;
        } else if (i < W3OFF) {
            int j = i - W2OFF, r = j / 36, c = j - r * 36;
            v = (c < 32) ? W2[r * 32 + c] : 0.f;
        } else {
            int j = i - W3OFF, r = j / 36, c = j - r * 36;
            v = (r < 3 && c < 32) ? W3[r * 32 + c] : 0.f;
        }
        w[i] = (_Float16)v;
    }
}

// ---- prep kernels ----
__global__ __launch_bounds__(256) void pconv_kernel(
    const float* __restrict__ u_plane, const float* __restrict__ h_plane,
    const float* __restrict__ d_plane, const float* __restrict__ W0,
    const float* __restrict__ W1, const float* __restrict__ W2,
    const float* __restrict__ W3, _Float16* __restrict__ dst) {
    const int gid = blockIdx.x * 256 + threadIdx.x;
    const int gsz = gridDim.x * 256;
    for (int i = gid; i < UHALVES / 8; i += gsz) cvt_chunk(u_plane, dst, i);
    for (int i = gid; i < AHALVES / 8; i += gsz) cvt_chunk(h_plane, dst + UHALVES, i);
    for (int i = gid; i < AHALVES / 8; i += gsz) cvt_chunk(d_plane, dst + UHALVES + AHALVES, i);
    if (blockIdx.x == 0) wblob_fill(W0, W1, W2, W3, dst + WOFF, threadIdx.x, 256);
}

__global__ __launch_bounds__(256) void wprep_kernel(
    const float* __restrict__ W0, const float* __restrict__ W1,
    const float* __restrict__ W2, const float* __restrict__ W3,
    _Float16* __restrict__ wdst) {
    wblob_fill(W0, W1, W2, W3, wdst, threadIdx.x, 256);
}

// Bilerp address+weight bundle (arithmetic identical to R5..R15)
struct GA { int o0, o1, o2, o3; float w00, w10, w01, w11; };

__device__ __forceinline__ GA mkU(float ux, float uy) {
    GA g;
    float u = clamp01(ux) * (float)(U_RESV - 1);
    float v = clamp01(uy) * (float)(U_RESV - 1);
    float x0f = floorf(u), y0f = floorf(v);
    int x0 = (int)x0f, y0 = (int)y0f;
    int x1 = min(x0 + 1, U_RESV - 1), y1 = min(y0 + 1, U_RESV - 1);
    float ur = u - x0f, vr = v - y0f;
    g.w00 = (1.0f - ur) * (1.0f - vr); g.w10 = ur * (1.0f - vr);
    g.w01 = (1.0f - ur) * vr;          g.w11 = ur * vr;
    g.o0 = (y0 * U_RESV + x0) * 8;
    g.o1 = (y0 * U_RESV + x1) * 8;
    g.o2 = (y1 * U_RESV + x0) * 8;
    g.o3 = (y1 * U_RESV + x1) * 8;
    return g;
}
__device__ __forceinline__ GA mkA(float uu, float vv) {
    GA g;
    float uf = uu - floorf(uu);
    float u = uf * (float)A_RESV;                 // in [0,50)
    float v = clamp01(vv) * (float)(A_RESV - 1);
    float x0f = floorf(u), y0f = floorf(v);
    int x0 = (int)x0f;
    int x1 = x0 + 1; if (x1 == A_RESV) x1 = 0;
    int y0 = (int)y0f;
    int y1 = min(y0 + 1, A_RESV - 1);
    float ur = u - x0f, vr = v - y0f;
    g.w00 = (1.0f - ur) * (1.0f - vr); g.w10 = ur * (1.0f - vr);
    g.w01 = (1.0f - ur) * vr;          g.w11 = ur * vr;
    g.o0 = (y0 * A_RESV + x0) * 8;
    g.o1 = (y0 * A_RESV + x1) * 8;
    g.o2 = (y1 * A_RESV + x0) * 8;
    g.o3 = (y1 * A_RESV + x1) * 8;
    return g;
}

__device__ __forceinline__ void blend8(half8 a, half8 b, half8 c, half8 d,
                                       const GA& g, float* f) {
#pragma unroll
    for (int i = 0; i < 8; ++i) {
        float r = (float)a[i] * g.w00;
        r = fmaf((float)b[i], g.w10, r);
        r = fmaf((float)c[i], g.w01, r);
        r = fmaf((float)d[i], g.w11, r);
        f[i] = r;
    }
}

// R16: R13 per-point code inside a K=4 outer loop. 512 threads x 4 iters =
// 2048 pts/block; grid 1024 = exactly 4 blocks/CU (LDS 36.2KB). Weights
// staged ONCE per block + single barrier; iterations are barrier-free (feat
// LDS rows are wave-private; lgkmcnt(0) handoff, verified R8+). Waves drift
// into staggered phases; block ramp/drain amortized 4x; VGPR stays ~R13
// (no pipeline state doubling — R15's VGPR 84 collapsed occupancy to 24%).
// MFMA maps (verified R4..R15, 16x16x16 f16):
//   A: lane 16q+c holds A[row=c][k=4q+e];  B: lane 16q+c holds B[k=4q+e][col=c]
//   D: lane 16q+c reg r holds D[row=4q+r][col=c]
// Chain identity: D reg r == next-layer B elem e. Wave owns 64 pts/iter.

template <bool F16P, int K>
__global__ __launch_bounds__(512, 1) void tpmlp_kernel(
    const float* __restrict__ x,
    const void* __restrict__ u_tex,
    const void* __restrict__ h_tex,
    const void* __restrict__ d_tex,
    const _Float16* __restrict__ wsw,
    float* __restrict__ out) {
    const int tid  = threadIdx.x;
    const int lane = tid & 63;
    const int wv   = tid >> 6;
    const int q    = lane >> 4;
    const int c15  = lane & 15;

    __shared__ __align__(16) _Float16 fl[512 * 28];   // feat: wave-private 64-row slices
    __shared__ __align__(16) _Float16 wl[WTOT];

    // ---- stage weights once; the ONLY block barrier ----
    {
        const uint4* src = (const uint4*)wsw;
        uint4 w_a;
        if (tid < 472) w_a = src[tid];
        if (tid < 472) ((uint4*)wl)[tid] = w_a;
    }
    __syncthreads();

    const _Float16* wb  = fl + (size_t)wv * 64 * 28;
    const _Float16* w0l = wl + W0OFF;
    const _Float16* w1l = wl + W1OFF;
    const _Float16* w2l = wl + W2OFF;
    const _Float16* w3l = wl + W3OFF;
    const size_t blkbase = (size_t)blockIdx.x * (512 * K);

#pragma unroll 1
    for (int it = 0; it < K; ++it) {
        const size_t P = blkbase + (size_t)it * 512 + tid;

        // ---- x load ----
        const float2* xp = (const float2*)(x + P * 6);
        float2 p01v = xp[0], p23v = xp[1], p45v = xp[2];

        // ---- addresses ----
        GA gU = mkU(p01v.x, p01v.y);
        GA gH = mkA(p23v.y, p23v.x);
        GA gD = mkA(p45v.y, p45v.x);

        // ---- issue ALL 12 texel loads ----
        half8 gU0, gU1, gU2, gU3, gH0, gH1, gH2, gH3, gD0, gD1, gD2, gD3;
        float4 sU0, sU1, sU2, sU3, sH0, sH1, sH2, sH3, sD0, sD1, sD2, sD3;
        float4 rU0, rU1, rU2, rU3, rH0, rH1, rH2, rH3, rD0, rD1, rD2, rD3;
        if constexpr (F16P) {
            const _Float16* up = (const _Float16*)u_tex;
            const _Float16* hp = (const _Float16*)h_tex;
            const _Float16* dp = (const _Float16*)d_tex;
            gU0 = *(const half8*)(up + gU.o0);
            gU1 = *(const half8*)(up + gU.o1);
            gU2 = *(const half8*)(up + gU.o2);
            gU3 = *(const half8*)(up + gU.o3);
            gH0 = *(const half8*)(hp + gH.o0);
            gH1 = *(const half8*)(hp + gH.o1);
            gH2 = *(const half8*)(hp + gH.o2);
            gH3 = *(const half8*)(hp + gH.o3);
            gD0 = *(const half8*)(dp + gD.o0);
            gD1 = *(const half8*)(dp + gD.o1);
            gD2 = *(const half8*)(dp + gD.o2);
            gD3 = *(const half8*)(dp + gD.o3);
        } else {
            const float* up = (const float*)u_tex;
            const float* hp = (const float*)h_tex;
            const float* dp = (const float*)d_tex;
            sU0 = *(const float4*)(up + gU.o0); rU0 = *(const float4*)(up + gU.o0 + 4);
            sU1 = *(const float4*)(up + gU.o1); rU1 = *(const float4*)(up + gU.o1 + 4);
            sU2 = *(const float4*)(up + gU.o2); rU2 = *(const float4*)(up + gU.o2 + 4);
            sU3 = *(const float4*)(up + gU.o3); rU3 = *(const float4*)(up + gU.o3 + 4);
            sH0 = *(const float4*)(hp + gH.o0); rH0 = *(const float4*)(hp + gH.o0 + 4);
            sH1 = *(const float4*)(hp + gH.o1); rH1 = *(const float4*)(hp + gH.o1 + 4);
            sH2 = *(const float4*)(hp + gH.o2); rH2 = *(const float4*)(hp + gH.o2 + 4);
            sH3 = *(const float4*)(hp + gH.o3); rH3 = *(const float4*)(hp + gH.o3 + 4);
            sD0 = *(const float4*)(dp + gD.o0); rD0 = *(const float4*)(dp + gD.o0 + 4);
            sD1 = *(const float4*)(dp + gD.o1); rD1 = *(const float4*)(dp + gD.o1 + 4);
            sD2 = *(const float4*)(dp + gD.o2); rD2 = *(const float4*)(dp + gD.o2 + 4);
            sD3 = *(const float4*)(dp + gD.o3); rD3 = *(const float4*)(dp + gD.o3 + 4);
        }
        __builtin_amdgcn_sched_barrier(0);

        // ---- bilerp (exact verified FMA order) ----
        float fU[8], fH[8], fD[8];
        if constexpr (F16P) {
            blend8(gU0, gU1, gU2, gU3, gU, fU);
            blend8(gH0, gH1, gH2, gH3, gH, fH);
            blend8(gD0, gD1, gD2, gD3, gD, fD);
        } else {
#pragma unroll
            for (int i = 0; i < 8; ++i) {
                const float* a = i < 4 ? (const float*)&sU0 : (const float*)&rU0;
                const float* b = i < 4 ? (const float*)&sU1 : (const float*)&rU1;
                const float* c = i < 4 ? (const float*)&sU2 : (const float*)&rU2;
                const float* d = i < 4 ? (const float*)&sU3 : (const float*)&rU3;
                int k = i & 3;
                float r = a[k] * gU.w00;
                r = fmaf(b[k], gU.w10, r);
                r = fmaf(c[k], gU.w01, r);
                r = fmaf(d[k], gU.w11, r);
                fU[i] = r;
            }
#pragma unroll
            for (int i = 0; i < 8; ++i) {
                const float* a = i < 4 ? (const float*)&sH0 : (const float*)&rH0;
                const float* b = i < 4 ? (const float*)&sH1 : (const float*)&rH1;
                const float* c = i < 4 ? (const float*)&sH2 : (const float*)&rH2;
                const float* d = i < 4 ? (const float*)&sH3 : (const float*)&rH3;
                int k = i & 3;
                float r = a[k] * gH.w00;
                r = fmaf(b[k], gH.w10, r);
                r = fmaf(c[k], gH.w01, r);
                r = fmaf(d[k], gH.w11, r);
                fH[i] = r;
            }
#pragma unroll
            for (int i = 0; i < 8; ++i) {
                const float* a = i < 4 ? (const float*)&sD0 : (const float*)&rD0;
                const float* b = i < 4 ? (const float*)&sD1 : (const float*)&rD1;
                const float* c = i < 4 ? (const float*)&sD2 : (const float*)&rD2;
                const float* d = i < 4 ? (const float*)&sD3 : (const float*)&rD3;
                int k = i & 3;
                float r = a[k] * gD.w00;
                r = fmaf(b[k], gD.w10, r);
                r = fmaf(c[k], gD.w01, r);
                r = fmaf(d[k], gD.w11, r);
                fD[i] = r;
            }
        }

        // ---- feat -> f16 -> LDS (row = my point; wave-private slice) ----
        {
            _Float16* row = fl + tid * 28;
            half8 hU, hH, hD;
#pragma unroll
            for (int i = 0; i < 8; ++i) {
                hU[i] = (_Float16)fU[i];
                hH[i] = (_Float16)fH[i];
                hD[i] = (_Float16)fD[i];
            }
            *(half8*)(row)      = hU;   // ch 0-7
            *(half8*)(row + 8)  = hH;   // ch 8-15
            *(half8*)(row + 16) = hD;   // ch 16-23
        }
        // wave-local handoff (same-wave lockstep; verified R8..R15)
        asm volatile("s_waitcnt lgkmcnt(0)" ::: "memory");
        __builtin_amdgcn_sched_barrier(0);

        // ---- MLP: wave owns 64 points, j-tiles {0..3} ----
        floatx4 zf; zf[0] = 0.f; zf[1] = 0.f; zf[2] = 0.f; zf[3] = 0.f;
        half4 b0[4], b1[4];
#pragma unroll
        for (int j = 0; j < 4; ++j) {
            const _Float16* r = wb + (size_t)(j * 16 + c15) * 28;
            b0[j] = *(const half4*)(r + q * 4);
            b1[j] = (q < 2) ? *(const half4*)(r + 16 + q * 4) : zero4();
        }

        floatx4 cc[2][4];
        // layer 0 (K=24: k-half1 zero for q>=2 on both operands; W0 stride 28)
#pragma unroll
        for (int m = 0; m < 2; ++m) {
            half4 a0 = *(const half4*)(w0l + (size_t)(16 * m + c15) * 28 + q * 4);
            half4 a1 = (q < 2) ? *(const half4*)(w0l + (size_t)(16 * m + c15) * 28 + 16 + q * 4) : zero4();
#pragma unroll
            for (int j = 0; j < 4; ++j)
                cc[m][j] = mfma16(a1, b1[j], mfma16(a0, b0[j], zf));
        }
#pragma unroll
        for (int j = 0; j < 4; ++j) {
#pragma unroll
            for (int e = 0; e < 4; ++e) {
                b0[j][e] = (_Float16)cc[0][j][e];
                b1[j][e] = (_Float16)cc[1][j][e];
            }
            b0[j] = relu4(b0[j]);
            b1[j] = relu4(b1[j]);
        }

        // layer 1
#pragma unroll
        for (int m = 0; m < 2; ++m) {
            half4 a0 = *(const half4*)(w1l + (size_t)(16 * m + c15) * 36 + q * 4);
            half4 a1 = *(const half4*)(w1l + (size_t)(16 * m + c15) * 36 + 16 + q * 4);
#pragma unroll
            for (int j = 0; j < 4; ++j)
                cc[m][j] = mfma16(a1, b1[j], mfma16(a0, b0[j], zf));
        }
#pragma unroll
        for (int j = 0; j < 4; ++j) {
#pragma unroll
            for (int e = 0; e < 4; ++e) {
                b0[j][e] = (_Float16)cc[0][j][e];
                b1[j][e] = (_Float16)cc[1][j][e];
            }
            b0[j] = relu4(b0[j]);
            b1[j] = relu4(b1[j]);
        }

        // layer 2
#pragma unroll
        for (int m = 0; m < 2; ++m) {
            half4 a0 = *(const half4*)(w2l + (size_t)(16 * m + c15) * 36 + q * 4);
            half4 a1 = *(const half4*)(w2l + (size_t)(16 * m + c15) * 36 + 16 + q * 4);
#pragma unroll
            for (int j = 0; j < 4; ++j)
                cc[m][j] = mfma16(a1, b1[j], mfma16(a0, b0[j], zf));
        }
#pragma unroll
        for (int j = 0; j < 4; ++j) {
#pragma unroll
            for (int e = 0; e < 4; ++e) {
                b0[j][e] = (_Float16)cc[0][j][e];
                b1[j][e] = (_Float16)cc[1][j][e];
            }
            b0[j] = relu4(b0[j]);
            b1[j] = relu4(b1[j]);
        }

        // layer 3 (rows 0-2 valid; w3l rows 3-15 zero)
        floatx4 c3[4];
        {
            half4 a0 = *(const half4*)(w3l + (size_t)c15 * 36 + q * 4);
            half4 a1 = *(const half4*)(w3l + (size_t)c15 * 36 + 16 + q * 4);
#pragma unroll
            for (int j = 0; j < 4; ++j)
                c3[j] = mfma16(a1, b1[j], mfma16(a0, b0[j], zf));
        }

        if (lane < 16) {
            const size_t base = blkbase + (size_t)it * 512 + (size_t)wv * 64;
#pragma unroll
            for (int j = 0; j < 4; ++j) {
                size_t p = base + (size_t)j * 16 + lane;
                float* o = out + p * 3;
                o[0] = c3[j][0];
                o[1] = c3[j][1];
                o[2] = c3[j][2];
            }
        }
    }
}

extern "C" void kernel_launch(void* const* d_in, const int* in_sizes, int n_in,
                              void* d_out, int out_size, void* d_ws, size_t ws_size,
                              hipStream_t stream) {
    const float* x       = (const float*)d_in[0];
    const float* u_plane = (const float*)d_in[1];
    const float* h_plane = (const float*)d_in[2];
    const float* d_plane = (const float*)d_in[3];
    const float* W0      = (const float*)d_in[4];
    const float* W1      = (const float*)d_in[5];
    const float* W2      = (const float*)d_in[6];
    const float* W3      = (const float*)d_in[7];
    float* out = (float*)d_out;
    _Float16* wsw = (_Float16*)d_ws;

    int n = in_sizes[0] / 6;          // 2^21
    constexpr int K = 4;

    const size_t need = ((size_t)WOFF + WTOT) * 2;
    if (ws_size >= need) {
        pconv_kernel<<<648, 256, 0, stream>>>(u_plane, h_plane, d_plane,
                                              W0, W1, W2, W3, wsw);
        int grid = n / (512 * K);     // 1024 blocks = 4 per CU
        tpmlp_kernel<true, K><<<grid, 512, 0, stream>>>(
            x, (const void*)wsw, (const void*)(wsw + UHALVES),
            (const void*)(wsw + UHALVES + AHALVES), wsw + WOFF, out);
    } else {
        wprep_kernel<<<1, 256, 0, stream>>>(W0, W1, W2, W3, wsw);
        int grid = n / (512 * K);
        tpmlp_kernel<false, K><<<grid, 512, 0, stream>>>(
            x, (const void*)u_plane, (const void*)h_plane, (const void*)d_plane,
            wsw, out);
    }
}

// Round 17
// 67.012 us; speedup vs baseline: 1.1669x; 1.1109x over previous
//
#include <hip/hip_runtime.h>

typedef _Float16 half4 __attribute__((ext_vector_type(4)));
typedef _Float16 half8 __attribute__((ext_vector_type(8)));
typedef float floatx4 __attribute__((ext_vector_type(4)));

#define U_RESV 400
#define A_RESV 50

#define UHALVES (U_RESV * U_RESV * 8)   // 1,280,000
#define AHALVES (A_RESV * A_RESV * 8)   // 20,000
#define WOFF    (UHALVES + 2 * AHALVES) // weights offset (halves)
// W0 32x28 (cols>=24 zero) | W1 32x36 | W2 32x36 | W3 16x36 (rows>=3 zero)
#define W0OFF   0
#define W1OFF   896
#define W2OFF   2048
#define W3OFF   3200
#define WTOT    3776                    // halves; 7552 B = 472 x 16 B

__device__ __forceinline__ float clamp01(float x) { return fminf(fmaxf(x, 0.0f), 1.0f); }

__device__ __forceinline__ floatx4 mfma16(half4 a, half4 b, floatx4 c) {
    return __builtin_amdgcn_mfma_f32_16x16x16f16(a, b, c, 0, 0, 0);
}
__device__ __forceinline__ half4 zero4() {
    half4 h; h[0] = h[1] = h[2] = h[3] = (_Float16)0.f; return h;
}
__device__ __forceinline__ half4 relu4(half4 v) {
#if __has_builtin(__builtin_elementwise_max)
    return __builtin_elementwise_max(v, zero4());
#else
    half4 r;
#pragma unroll
    for (int i = 0; i < 4; ++i) r[i] = v[i] > (_Float16)0.f ? v[i] : (_Float16)0.f;
    return r;
#endif
}

__device__ __forceinline__ void cvt_chunk(const float* __restrict__ src,
                                          _Float16* __restrict__ dst, int i) {
    float4 a = *(const float4*)(src + (size_t)i * 8);
    float4 b = *(const float4*)(src + (size_t)i * 8 + 4);
    half8 h;
    h[0] = (_Float16)a.x; h[1] = (_Float16)a.y; h[2] = (_Float16)a.z; h[3] = (_Float16)a.w;
    h[4] = (_Float16)b.x; h[5] = (_Float16)b.y; h[6] = (_Float16)b.z; h[7] = (_Float16)b.w;
    *(half8*)(dst + (size_t)i * 8) = h;
}

__device__ __forceinline__ void wblob_fill(const float* __restrict__ W0,
                                           const float* __restrict__ W1,
                                           const float* __restrict__ W2,
                                           const float* __restrict__ W3,
                                           _Float16* __restrict__ w, int tid, int nthr) {
    for (int i = tid; i < WTOT; i += nthr) {
        float v;
        if (i < W1OFF) {
            int r = i / 28, c = i - r * 28;
            v = (c < 24) ? W0[r * 24 + c] : 0.f;
        } else if (i < W2OFF) {
            int j = i - W1OFF, r = j / 36, c = j - r * 36;
            v = (c < 32) ? W1[r * 32 + c] : 0.f;
        } else if (i < W3OFF) {
            int j = i - W2OFF, r = j / 36, c = j - r * 36;
            v = (c < 32) ? W2[r * 32 + c] : 0.f;
        } else {
            int j = i - W3OFF, r = j / 36, c = j - r * 36;
            v = (r < 3 && c < 32) ? W3[r * 32 + c] : 0.f;
        }
        w[i] = (_Float16)v;
    }
}

// ---- prep kernels ----
__global__ __launch_bounds__(256) void pconv_kernel(
    const float* __restrict__ u_plane, const float* __restrict__ h_plane,
    const float* __restrict__ d_plane, const float* __restrict__ W0,
    const float* __restrict__ W1, const float* __restrict__ W2,
    const float* __restrict__ W3, _Float16* __restrict__ dst) {
    const int gid = blockIdx.x * 256 + threadIdx.x;
    const int gsz = gridDim.x * 256;
    for (int i = gid; i < UHALVES / 8; i += gsz) cvt_chunk(u_plane, dst, i);
    for (int i = gid; i < AHALVES / 8; i += gsz) cvt_chunk(h_plane, dst + UHALVES, i);
    for (int i = gid; i < AHALVES / 8; i += gsz) cvt_chunk(d_plane, dst + UHALVES + AHALVES, i);
    if (blockIdx.x == 0) wblob_fill(W0, W1, W2, W3, dst + WOFF, threadIdx.x, 256);
}

__global__ __launch_bounds__(256) void wprep_kernel(
    const float* __restrict__ W0, const float* __restrict__ W1,
    const float* __restrict__ W2, const float* __restrict__ W3,
    _Float16* __restrict__ wdst) {
    wblob_fill(W0, W1, W2, W3, wdst, threadIdx.x, 256);
}

// Bilerp address+weight bundle (arithmetic identical to R5..R16)
struct GA { int o0, o1, o2, o3; float w00, w10, w01, w11; };

__device__ __forceinline__ GA mkU(float ux, float uy) {
    GA g;
    float u = clamp01(ux) * (float)(U_RESV - 1);
    float v = clamp01(uy) * (float)(U_RESV - 1);
    float x0f = floorf(u), y0f = floorf(v);
    int x0 = (int)x0f, y0 = (int)y0f;
    int x1 = min(x0 + 1, U_RESV - 1), y1 = min(y0 + 1, U_RESV - 1);
    float ur = u - x0f, vr = v - y0f;
    g.w00 = (1.0f - ur) * (1.0f - vr); g.w10 = ur * (1.0f - vr);
    g.w01 = (1.0f - ur) * vr;          g.w11 = ur * vr;
    g.o0 = (y0 * U_RESV + x0) * 8;
    g.o1 = (y0 * U_RESV + x1) * 8;
    g.o2 = (y1 * U_RESV + x0) * 8;
    g.o3 = (y1 * U_RESV + x1) * 8;
    return g;
}
__device__ __forceinline__ GA mkA(float uu, float vv) {
    GA g;
    float uf = uu - floorf(uu);
    float u = uf * (float)A_RESV;                 // in [0,50)
    float v = clamp01(vv) * (float)(A_RESV - 1);
    float x0f = floorf(u), y0f = floorf(v);
    int x0 = (int)x0f;
    int x1 = x0 + 1; if (x1 == A_RESV) x1 = 0;
    int y0 = (int)y0f;
    int y1 = min(y0 + 1, A_RESV - 1);
    float ur = u - x0f, vr = v - y0f;
    g.w00 = (1.0f - ur) * (1.0f - vr); g.w10 = ur * (1.0f - vr);
    g.w01 = (1.0f - ur) * vr;          g.w11 = ur * vr;
    g.o0 = (y0 * A_RESV + x0) * 8;
    g.o1 = (y0 * A_RESV + x1) * 8;
    g.o2 = (y1 * A_RESV + x0) * 8;
    g.o3 = (y1 * A_RESV + x1) * 8;
    return g;
}

__device__ __forceinline__ void blend8(half8 a, half8 b, half8 c, half8 d,
                                       const GA& g, float* f) {
#pragma unroll
    for (int i = 0; i < 8; ++i) {
        float r = (float)a[i] * g.w00;
        r = fmaf((float)b[i], g.w10, r);
        r = fmaf((float)c[i], g.w01, r);
        r = fmaf((float)d[i], g.w11, r);
        f[i] = r;
    }
}

// R17: H and D planes staged ENTIRELY in LDS (78.1 KB) -> 8 of 12 texel
// gathers become ds_read_b128 (LDS pipe, ~128B/cyc/CU) instead of L1/TA
// line-services (the ~43us floor that R11-R16 plateaued on). 1024-thread
// blocks: feat 57.3KB + H/D 78.1KB + W 7.4KB = 142.8KB -> 1 block/CU =
// 16 waves (same achieved occupancy as R13). launch_bounds(1024,4): VGPR
// cap 128 (R12's spill was cap=64; need ~50). K=2 iters amortize staging.
// Per-point arithmetic byte-identical to R13/R16.
// MFMA maps (verified R4..R16, 16x16x16 f16):
//   A: lane 16q+c holds A[row=c][k=4q+e];  B: lane 16q+c holds B[k=4q+e][col=c]
//   D: lane 16q+c reg r holds D[row=4q+r][col=c]
// Chain identity: D reg r == next-layer B elem e. Wave owns 64 pts/iter.

template <int K>
__global__ __launch_bounds__(1024, 4) void tpmlp_kernel(
    const float* __restrict__ x,
    const _Float16* __restrict__ up,      // f16 U plane (ws)
    const _Float16* __restrict__ hdsrc,   // f16 H then D, contiguous (ws)
    const _Float16* __restrict__ wsw,     // f16 weight blob (ws)
    float* __restrict__ out) {
    const int tid  = threadIdx.x;
    const int lane = tid & 63;
    const int wv   = tid >> 6;
    const int q    = lane >> 4;
    const int c15  = lane & 15;

    __shared__ __align__(16) _Float16 fl[1024 * 28];      // feat: wave-private rows, 57.3 KB
    __shared__ __align__(16) _Float16 hdl[2 * AHALVES];   // H then D, 78.1 KB
    __shared__ __align__(16) _Float16 wl[WTOT];           // 7.4 KB

    // ---- stage H+D (5000 uint4, coalesced) + weights; ONE barrier ----
    {
        const uint4* src = (const uint4*)hdsrc;
        uint4* dst = (uint4*)hdl;
        for (int i = tid; i < (2 * AHALVES) / 8; i += 1024) dst[i] = src[i];
        if (tid < 472) ((uint4*)wl)[tid] = ((const uint4*)wsw)[tid];
    }
    __syncthreads();

    const _Float16* hp  = hdl;
    const _Float16* dp  = hdl + AHALVES;
    const _Float16* wb  = fl + (size_t)wv * 64 * 28;
    const _Float16* w0l = wl + W0OFF;
    const _Float16* w1l = wl + W1OFF;
    const _Float16* w2l = wl + W2OFF;
    const _Float16* w3l = wl + W3OFF;
    const size_t blkbase = (size_t)blockIdx.x * (1024 * K);

#pragma unroll 1
    for (int it = 0; it < K; ++it) {
        const size_t P = blkbase + (size_t)it * 1024 + tid;

        // ---- x load ----
        const float2* xp = (const float2*)(x + P * 6);
        float2 p01v = xp[0], p23v = xp[1], p45v = xp[2];

        // ---- addresses ----
        GA gU = mkU(p01v.x, p01v.y);
        GA gH = mkA(p23v.y, p23v.x);
        GA gD = mkA(p45v.y, p45v.x);

        // ---- issue the 4 U texel loads (global, L2); pin them in flight ----
        half8 tU0 = *(const half8*)(up + gU.o0);
        half8 tU1 = *(const half8*)(up + gU.o1);
        half8 tU2 = *(const half8*)(up + gU.o2);
        half8 tU3 = *(const half8*)(up + gU.o3);
        __builtin_amdgcn_sched_barrier(0);

        // ---- H/D texels from LDS (consumed while U loads are in flight) ----
        half8 tH0 = *(const half8*)(hp + gH.o0);
        half8 tH1 = *(const half8*)(hp + gH.o1);
        half8 tH2 = *(const half8*)(hp + gH.o2);
        half8 tH3 = *(const half8*)(hp + gH.o3);
        half8 tD0 = *(const half8*)(dp + gD.o0);
        half8 tD1 = *(const half8*)(dp + gD.o1);
        half8 tD2 = *(const half8*)(dp + gD.o2);
        half8 tD3 = *(const half8*)(dp + gD.o3);

        // ---- bilerp (exact verified per-channel FMA order) ----
        float fU[8], fH[8], fD[8];
        blend8(tH0, tH1, tH2, tH3, gH, fH);
        blend8(tD0, tD1, tD2, tD3, gD, fD);
        blend8(tU0, tU1, tU2, tU3, gU, fU);

        // ---- feat -> f16 -> LDS (row = my point; wave-private slice) ----
        {
            _Float16* row = fl + tid * 28;
            half8 hU, hH, hD;
#pragma unroll
            for (int i = 0; i < 8; ++i) {
                hU[i] = (_Float16)fU[i];
                hH[i] = (_Float16)fH[i];
                hD[i] = (_Float16)fD[i];
            }
            *(half8*)(row)      = hU;   // ch 0-7
            *(half8*)(row + 8)  = hH;   // ch 8-15
            *(half8*)(row + 16) = hD;   // ch 16-23
        }
        // wave-local handoff (same-wave lockstep; verified R8..R16)
        asm volatile("s_waitcnt lgkmcnt(0)" ::: "memory");
        __builtin_amdgcn_sched_barrier(0);

        // ---- MLP: wave owns 64 points, j-tiles {0..3} ----
        floatx4 zf; zf[0] = 0.f; zf[1] = 0.f; zf[2] = 0.f; zf[3] = 0.f;
        half4 b0[4], b1[4];
#pragma unroll
        for (int j = 0; j < 4; ++j) {
            const _Float16* r = wb + (size_t)(j * 16 + c15) * 28;
            b0[j] = *(const half4*)(r + q * 4);
            b1[j] = (q < 2) ? *(const half4*)(r + 16 + q * 4) : zero4();
        }

        floatx4 cc[2][4];
        // layer 0 (K=24: k-half1 zero for q>=2 on both operands; W0 stride 28)
#pragma unroll
        for (int m = 0; m < 2; ++m) {
            half4 a0 = *(const half4*)(w0l + (size_t)(16 * m + c15) * 28 + q * 4);
            half4 a1 = (q < 2) ? *(const half4*)(w0l + (size_t)(16 * m + c15) * 28 + 16 + q * 4) : zero4();
#pragma unroll
            for (int j = 0; j < 4; ++j)
                cc[m][j] = mfma16(a1, b1[j], mfma16(a0, b0[j], zf));
        }
#pragma unroll
        for (int j = 0; j < 4; ++j) {
#pragma unroll
            for (int e = 0; e < 4; ++e) {
                b0[j][e] = (_Float16)cc[0][j][e];
                b1[j][e] = (_Float16)cc[1][j][e];
            }
            b0[j] = relu4(b0[j]);
            b1[j] = relu4(b1[j]);
        }

        // layer 1
#pragma unroll
        for (int m = 0; m < 2; ++m) {
            half4 a0 = *(const half4*)(w1l + (size_t)(16 * m + c15) * 36 + q * 4);
            half4 a1 = *(const half4*)(w1l + (size_t)(16 * m + c15) * 36 + 16 + q * 4);
#pragma unroll
            for (int j = 0; j < 4; ++j)
                cc[m][j] = mfma16(a1, b1[j], mfma16(a0, b0[j], zf));
        }
#pragma unroll
        for (int j = 0; j < 4; ++j) {
#pragma unroll
            for (int e = 0; e < 4; ++e) {
                b0[j][e] = (_Float16)cc[0][j][e];
                b1[j][e] = (_Float16)cc[1][j][e];
            }
            b0[j] = relu4(b0[j]);
            b1[j] = relu4(b1[j]);
        }

        // layer 2
#pragma unroll
        for (int m = 0; m < 2; ++m) {
            half4 a0 = *(const half4*)(w2l + (size_t)(16 * m + c15) * 36 + q * 4);
            half4 a1 = *(const half4*)(w2l + (size_t)(16 * m + c15) * 36 + 16 + q * 4);
#pragma unroll
            for (int j = 0; j < 4; ++j)
                cc[m][j] = mfma16(a1, b1[j], mfma16(a0, b0[j], zf));
        }
#pragma unroll
        for (int j = 0; j < 4; ++j) {
#pragma unroll
            for (int e = 0; e < 4; ++e) {
                b0[j][e] = (_Float16)cc[0][j][e];
                b1[j][e] = (_Float16)cc[1][j][e];
            }
            b0[j] = relu4(b0[j]);
            b1[j] = relu4(b1[j]);
        }

        // layer 3 (rows 0-2 valid; w3l rows 3-15 zero)
        floatx4 c3[4];
        {
            half4 a0 = *(const half4*)(w3l + (size_t)c15 * 36 + q * 4);
            half4 a1 = *(const half4*)(w3l + (size_t)c15 * 36 + 16 + q * 4);
#pragma unroll
            for (int j = 0; j < 4; ++j)
                c3[j] = mfma16(a1, b1[j], mfma16(a0, b0[j], zf));
        }

        if (lane < 16) {
            const size_t base = blkbase + (size_t)it * 1024 + (size_t)wv * 64;
#pragma unroll
            for (int j = 0; j < 4; ++j) {
                size_t p = base + (size_t)j * 16 + lane;
                float* o = out + p * 3;
                o[0] = c3[j][0];
                o[1] = c3[j][1];
                o[2] = c3[j][2];
            }
        }
    }
}

// ---- fallback (f32 planes, R13 structure; only if ws too small) ----
__global__ __launch_bounds__(512, 2) void tpmlp_f32(
    const float* __restrict__ x,
    const float* __restrict__ up,
    const float* __restrict__ hp,
    const float* __restrict__ dp,
    const _Float16* __restrict__ wsw,
    float* __restrict__ out) {
    const int tid  = threadIdx.x;
    const int lane = tid & 63;
    const int wv   = tid >> 6;
    const int q    = lane >> 4;
    const int c15  = lane & 15;

    __shared__ __align__(16) _Float16 fl[512 * 28];
    __shared__ __align__(16) _Float16 wl[WTOT];

    const size_t P = (size_t)blockIdx.x * 512 + tid;
    const float2* xp = (const float2*)(x + P * 6);
    float2 p01v = xp[0], p23v = xp[1], p45v = xp[2];

    uint4 w_a;
    if (tid < 472) w_a = ((const uint4*)wsw)[tid];

    GA gU = mkU(p01v.x, p01v.y);
    GA gH = mkA(p23v.y, p23v.x);
    GA gD = mkA(p45v.y, p45v.x);

    float4 sU0 = *(const float4*)(up + gU.o0); float4 rU0 = *(const float4*)(up + gU.o0 + 4);
    float4 sU1 = *(const float4*)(up + gU.o1); float4 rU1 = *(const float4*)(up + gU.o1 + 4);
    float4 sU2 = *(const float4*)(up + gU.o2); float4 rU2 = *(const float4*)(up + gU.o2 + 4);
    float4 sU3 = *(const float4*)(up + gU.o3); float4 rU3 = *(const float4*)(up + gU.o3 + 4);
    float4 sH0 = *(const float4*)(hp + gH.o0); float4 rH0 = *(const float4*)(hp + gH.o0 + 4);
    float4 sH1 = *(const float4*)(hp + gH.o1); float4 rH1 = *(const float4*)(hp + gH.o1 + 4);
    float4 sH2 = *(const float4*)(hp + gH.o2); float4 rH2 = *(const float4*)(hp + gH.o2 + 4);
    float4 sH3 = *(const float4*)(hp + gH.o3); float4 rH3 = *(const float4*)(hp + gH.o3 + 4);
    float4 sD0 = *(const float4*)(dp + gD.o0); float4 rD0 = *(const float4*)(dp + gD.o0 + 4);
    float4 sD1 = *(const float4*)(dp + gD.o1); float4 rD1 = *(const float4*)(dp + gD.o1 + 4);
    float4 sD2 = *(const float4*)(dp + gD.o2); float4 rD2 = *(const float4*)(dp + gD.o2 + 4);
    float4 sD3 = *(const float4*)(dp + gD.o3); float4 rD3 = *(const float4*)(dp + gD.o3 + 4);
    __builtin_amdgcn_sched_barrier(0);

    if (tid < 472) ((uint4*)wl)[tid] = w_a;
    asm volatile("s_waitcnt lgkmcnt(0)" ::: "memory");
    __builtin_amdgcn_s_barrier();

    float fU[8], fH[8], fD[8];
#pragma unroll
    for (int i = 0; i < 8; ++i) {
        const float* a = i < 4 ? (const float*)&sU0 : (const float*)&rU0;
        const float* b = i < 4 ? (const float*)&sU1 : (const float*)&rU1;
        const float* c = i < 4 ? (const float*)&sU2 : (const float*)&rU2;
        const float* d = i < 4 ? (const float*)&sU3 : (const float*)&rU3;
        int k = i & 3;
        float r = a[k] * gU.w00;
        r = fmaf(b[k], gU.w10, r);
        r = fmaf(c[k], gU.w01, r);
        r = fmaf(d[k], gU.w11, r);
        fU[i] = r;
    }
#pragma unroll
    for (int i = 0; i < 8; ++i) {
        const float* a = i < 4 ? (const float*)&sH0 : (const float*)&rH0;
        const float* b = i < 4 ? (const float*)&sH1 : (const float*)&rH1;
        const float* c = i < 4 ? (const float*)&sH2 : (const float*)&rH2;
        const float* d = i < 4 ? (const float*)&sH3 : (const float*)&rH3;
        int k = i & 3;
        float r = a[k] * gH.w00;
        r = fmaf(b[k], gH.w10, r);
        r = fmaf(c[k], gH.w01, r);
        r = fmaf(d[k], gH.w11, r);
        fH[i] = r;
    }
#pragma unroll
    for (int i = 0; i < 8; ++i) {
        const float* a = i < 4 ? (const float*)&sD0 : (const float*)&rD0;
        const float* b = i < 4 ? (const float*)&sD1 : (const float*)&rD1;
        const float* c = i < 4 ? (const float*)&sD2 : (const float*)&rD2;
        const float* d = i < 4 ? (const float*)&sD3 : (const float*)&rD3;
        int k = i & 3;
        float r = a[k] * gD.w00;
        r = fmaf(b[k], gD.w10, r);
        r = fmaf(c[k], gD.w01, r);
        r = fmaf(d[k], gD.w11, r);
        fD[i] = r;
    }

    {
        _Float16* row = fl + tid * 28;
        half8 hU, hH, hD;
#pragma unroll
        for (int i = 0; i < 8; ++i) {
            hU[i] = (_Float16)fU[i];
            hH[i] = (_Float16)fH[i];
            hD[i] = (_Float16)fD[i];
        }
        *(half8*)(row)      = hU;
        *(half8*)(row + 8)  = hH;
        *(half8*)(row + 16) = hD;
    }
    asm volatile("s_waitcnt lgkmcnt(0)" ::: "memory");
    __builtin_amdgcn_sched_barrier(0);

    floatx4 zf; zf[0] = 0.f; zf[1] = 0.f; zf[2] = 0.f; zf[3] = 0.f;
    const _Float16* wb = fl + (size_t)wv * 64 * 28;
    const _Float16* w0l = wl + W0OFF;
    const _Float16* w1l = wl + W1OFF;
    const _Float16* w2l = wl + W2OFF;
    const _Float16* w3l = wl + W3OFF;

    half4 b0[4], b1[4];
#pragma unroll
    for (int j = 0; j < 4; ++j) {
        const _Float16* r = wb + (size_t)(j * 16 + c15) * 28;
        b0[j] = *(const half4*)(r + q * 4);
        b1[j] = (q < 2) ? *(const half4*)(r + 16 + q * 4) : zero4();
    }

    floatx4 cc[2][4];
#pragma unroll
    for (int m = 0; m < 2; ++m) {
        half4 a0 = *(const half4*)(w0l + (size_t)(16 * m + c15) * 28 + q * 4);
        half4 a1 = (q < 2) ? *(const half4*)(w0l + (size_t)(16 * m + c15) * 28 + 16 + q * 4) : zero4();
#pragma unroll
        for (int j = 0; j < 4; ++j)
            cc[m][j] = mfma16(a1, b1[j], mfma16(a0, b0[j], zf));
    }
#pragma unroll
    for (int j = 0; j < 4; ++j) {
#pragma unroll
        for (int e = 0; e < 4; ++e) {
            b0[j][e] = (_Float16)cc[0][j][e];
            b1[j][e] = (_Float16)cc[1][j][e];
        }
        b0[j] = relu4(b0[j]);
        b1[j] = relu4(b1[j]);
    }
#pragma unroll
    for (int m = 0; m < 2; ++m) {
        half4 a0 = *(const half4*)(w1l + (size_t)(16 * m + c15) * 36 + q * 4);
        half4 a1 = *(const half4*)(w1l + (size_t)(16 * m + c15) * 36 + 16 + q * 4);
#pragma unroll
        for (int j = 0; j < 4; ++j)
            cc[m][j] = mfma16(a1, b1[j], mfma16(a0, b0[j], zf));
    }
#pragma unroll
    for (int j = 0; j < 4; ++j) {
#pragma unroll
        for (int e = 0; e < 4; ++e) {
            b0[j][e] = (_Float16)cc[0][j][e];
            b1[j][e] = (_Float16)cc[1][j][e];
        }
        b0[j] = relu4(b0[j]);
        b1[j] = relu4(b1[j]);
    }
#pragma unroll
    for (int m = 0; m < 2; ++m) {
        half4 a0 = *(const half4*)(w2l + (size_t)(16 * m + c15) * 36 + q * 4);
        half4 a1 = *(const half4*)(w2l + (size_t)(16 * m + c15) * 36 + 16 + q * 4);
#pragma unroll
        for (int j = 0; j < 4; ++j)
            cc[m][j] = mfma16(a1, b1[j], mfma16(a0, b0[j], zf));
    }
#pragma unroll
    for (int j = 0; j < 4; ++j) {
#pragma unroll
        for (int e = 0; e < 4; ++e) {
            b0[j][e] = (_Float16)cc[0][j][e];
            b1[j][e] = (_Float16)cc[1][j][e];
        }
        b0[j] = relu4(b0[j]);
        b1[j] = relu4(b1[j]);
    }

    floatx4 c3[4];
    {
        half4 a0 = *(const half4*)(w3l + (size_t)c15 * 36 + q * 4);
        half4 a1 = *(const half4*)(w3l + (size_t)c15 * 36 + 16 + q * 4);
#pragma unroll
        for (int j = 0; j < 4; ++j)
            c3[j] = mfma16(a1, b1[j], mfma16(a0, b0[j], zf));
    }

    if (lane < 16) {
        const size_t base = (size_t)blockIdx.x * 512 + (size_t)wv * 64;
#pragma unroll
        for (int j = 0; j < 4; ++j) {
            size_t p = base + (size_t)j * 16 + lane;
            float* o = out + p * 3;
            o[0] = c3[j][0];
            o[1] = c3[j][1];
            o[2] = c3[j][2];
        }
    }
}

extern "C" void kernel_launch(void* const* d_in, const int* in_sizes, int n_in,
                              void* d_out, int out_size, void* d_ws, size_t ws_size,
                              hipStream_t stream) {
    const float* x       = (const float*)d_in[0];
    const float* u_plane = (const float*)d_in[1];
    const float* h_plane = (const float*)d_in[2];
    const float* d_plane = (const float*)d_in[3];
    const float* W0      = (const float*)d_in[4];
    const float* W1      = (const float*)d_in[5];
    const float* W2      = (const float*)d_in[6];
    const float* W3      = (const float*)d_in[7];
    float* out = (float*)d_out;
    _Float16* wsw = (_Float16*)d_ws;

    int n = in_sizes[0] / 6;          // 2^21
    constexpr int K = 2;

    const size_t need = ((size_t)WOFF + WTOT) * 2;
    if (ws_size >= need) {
        pconv_kernel<<<648, 256, 0, stream>>>(u_plane, h_plane, d_plane,
                                              W0, W1, W2, W3, wsw);
        int grid = n / (1024 * K);    // 1024 blocks
        tpmlp_kernel<K><<<grid, 1024, 0, stream>>>(
            x, wsw, wsw + UHALVES, wsw + WOFF, out);
    } else {
        wprep_kernel<<<1, 256, 0, stream>>>(W0, W1, W2, W3, wsw);
        tpmlp_f32<<<n / 512, 512, 0, stream>>>(
            x, u_plane, h_plane, d_plane, wsw, out);
    }
}

// Round 18
// 65.017 us; speedup vs baseline: 1.2027x; 1.0307x over previous
//
#include <hip/hip_runtime.h>

typedef _Float16 half4 __attribute__((ext_vector_type(4)));
typedef _Float16 half8 __attribute__((ext_vector_type(8)));
typedef float floatx4 __attribute__((ext_vector_type(4)));

#define U_RESV 400
#define A_RESV 50

#define UHALVES (U_RESV * U_RESV * 8)   // 1,280,000
#define AHALVES (A_RESV * A_RESV * 8)   // 20,000
#define WOFF    (UHALVES + 2 * AHALVES) // weights offset (halves)
// W0 32x28 (cols>=24 zero) | W1 32x36 | W2 32x36 | W3 16x36 (rows>=3 zero)
#define W0OFF   0
#define W1OFF   896
#define W2OFF   2048
#define W3OFF   3200
#define WTOT    3776                    // halves; 7552 B = 472 x 16 B

__device__ __forceinline__ float clamp01(float x) { return fminf(fmaxf(x, 0.0f), 1.0f); }

__device__ __forceinline__ floatx4 mfma16(half4 a, half4 b, floatx4 c) {
    return __builtin_amdgcn_mfma_f32_16x16x16f16(a, b, c, 0, 0, 0);
}
__device__ __forceinline__ half4 zero4() {
    half4 h; h[0] = h[1] = h[2] = h[3] = (_Float16)0.f; return h;
}
__device__ __forceinline__ half4 relu4(half4 v) {
#if __has_builtin(__builtin_elementwise_max)
    return __builtin_elementwise_max(v, zero4());
#else
    half4 r;
#pragma unroll
    for (int i = 0; i < 4; ++i) r[i] = v[i] > (_Float16)0.f ? v[i] : (_Float16)0.f;
    return r;
#endif
}

__device__ __forceinline__ void cvt_chunk(const float* __restrict__ src,
                                          _Float16* __restrict__ dst, int i) {
    float4 a = *(const float4*)(src + (size_t)i * 8);
    float4 b = *(const float4*)(src + (size_t)i * 8 + 4);
    half8 h;
    h[0] = (_Float16)a.x; h[1] = (_Float16)a.y; h[2] = (_Float16)a.z; h[3] = (_Float16)a.w;
    h[4] = (_Float16)b.x; h[5] = (_Float16)b.y; h[6] = (_Float16)b.z; h[7] = (_Float16)b.w;
    *(half8*)(dst + (size_t)i * 8) = h;
}

__device__ __forceinline__ void wblob_fill(const float* __restrict__ W0,
                                           const float* __restrict__ W1,
                                           const float* __restrict__ W2,
                                           const float* __restrict__ W3,
                                           _Float16* __restrict__ w, int tid, int nthr) {
    for (int i = tid; i < WTOT; i += nthr) {
        float v;
        if (i < W1OFF) {
            int r = i / 28, c = i - r * 28;
            v = (c < 24) ? W0[r * 24 + c] : 0.f;
        } else if (i < W2OFF) {
            int j = i - W1OFF, r = j / 36, c = j - r * 36;
            v = (c < 32) ? W1[r * 32 + c] : 0.f;
        } else if (i < W3OFF) {
            int j = i - W2OFF, r = j / 36, c = j - r * 36;
            v = (c < 32) ? W2[r * 32 + c] : 0.f;
        } else {
            int j = i - W3OFF, r = j / 36, c = j - r * 36;
            v = (r < 3 && c < 32) ? W3[r * 32 + c] : 0.f;
        }
        w[i] = (_Float16)v;
    }
}

// ---- prep kernels ----
__global__ __launch_bounds__(256) void pconv_kernel(
    const float* __restrict__ u_plane, const float* __restrict__ h_plane,
    const float* __restrict__ d_plane, const float* __restrict__ W0,
    const float* __restrict__ W1, const float* __restrict__ W2,
    const float* __restrict__ W3, _Float16* __restrict__ dst) {
    const int gid = blockIdx.x * 256 + threadIdx.x;
    const int gsz = gridDim.x * 256;
    for (int i = gid; i < UHALVES / 8; i += gsz) cvt_chunk(u_plane, dst, i);
    for (int i = gid; i < AHALVES / 8; i += gsz) cvt_chunk(h_plane, dst + UHALVES, i);
    for (int i = gid; i < AHALVES / 8; i += gsz) cvt_chunk(d_plane, dst + UHALVES + AHALVES, i);
    if (blockIdx.x == 0) wblob_fill(W0, W1, W2, W3, dst + WOFF, threadIdx.x, 256);
}

__global__ __launch_bounds__(256) void wprep_kernel(
    const float* __restrict__ W0, const float* __restrict__ W1,
    const float* __restrict__ W2, const float* __restrict__ W3,
    _Float16* __restrict__ wdst) {
    wblob_fill(W0, W1, W2, W3, wdst, threadIdx.x, 256);
}

// Bilerp address+weight bundle (arithmetic identical to R5..R17)
struct GA { int o0, o1, o2, o3; float w00, w10, w01, w11; };

__device__ __forceinline__ GA mkU(float ux, float uy) {
    GA g;
    float u = clamp01(ux) * (float)(U_RESV - 1);
    float v = clamp01(uy) * (float)(U_RESV - 1);
    float x0f = floorf(u), y0f = floorf(v);
    int x0 = (int)x0f, y0 = (int)y0f;
    int x1 = min(x0 + 1, U_RESV - 1), y1 = min(y0 + 1, U_RESV - 1);
    float ur = u - x0f, vr = v - y0f;
    g.w00 = (1.0f - ur) * (1.0f - vr); g.w10 = ur * (1.0f - vr);
    g.w01 = (1.0f - ur) * vr;          g.w11 = ur * vr;
    g.o0 = (y0 * U_RESV + x0) * 8;
    g.o1 = (y0 * U_RESV + x1) * 8;
    g.o2 = (y1 * U_RESV + x0) * 8;
    g.o3 = (y1 * U_RESV + x1) * 8;
    return g;
}
__device__ __forceinline__ GA mkA(float uu, float vv) {
    GA g;
    float uf = uu - floorf(uu);
    float u = uf * (float)A_RESV;                 // in [0,50)
    float v = clamp01(vv) * (float)(A_RESV - 1);
    float x0f = floorf(u), y0f = floorf(v);
    int x0 = (int)x0f;
    int x1 = x0 + 1; if (x1 == A_RESV) x1 = 0;
    int y0 = (int)y0f;
    int y1 = min(y0 + 1, A_RESV - 1);
    float ur = u - x0f, vr = v - y0f;
    g.w00 = (1.0f - ur) * (1.0f - vr); g.w10 = ur * (1.0f - vr);
    g.w01 = (1.0f - ur) * vr;          g.w11 = ur * vr;
    g.o0 = (y0 * A_RESV + x0) * 8;
    g.o1 = (y0 * A_RESV + x1) * 8;
    g.o2 = (y1 * A_RESV + x0) * 8;
    g.o3 = (y1 * A_RESV + x1) * 8;
    return g;
}

__device__ __forceinline__ void blend8(half8 a, half8 b, half8 c, half8 d,
                                       const GA& g, float* f) {
#pragma unroll
    for (int i = 0; i < 8; ++i) {
        float r = (float)a[i] * g.w00;
        r = fmaf((float)b[i], g.w10, r);
        r = fmaf((float)c[i], g.w01, r);
        r = fmaf((float)d[i], g.w11, r);
        f[i] = r;
    }
}

// R18: R17 (H/D in LDS — the 72.7->62 win) + software pipeline across K=4
// iterations. Occupancy is LDS-bound (1 block/CU = 16 waves) so pipeline
// VGPRs are FREE up to the (1024,4) cap of 128 (R15's occupancy collapse
// doesn't apply). x loaded depth-2 ahead; U addr+loads issued depth-1 ahead
// (ride through the previous iteration's MLP ~2000cy); H/D LDS reads stay
// in-iteration. Fully unrolled -> register rotation by renaming.
// Per-point arithmetic byte-identical to R13/R16/R17.
// MFMA maps (verified R4..R17, 16x16x16 f16):
//   A: lane 16q+c holds A[row=c][k=4q+e];  B: lane 16q+c holds B[k=4q+e][col=c]
//   D: lane 16q+c reg r holds D[row=4q+r][col=c]
// Chain identity: D reg r == next-layer B elem e. Wave owns 64 pts/iter.

template <int K>
__global__ __launch_bounds__(1024, 4) void tpmlp_kernel(
    const float* __restrict__ x,
    const _Float16* __restrict__ up,      // f16 U plane (ws)
    const _Float16* __restrict__ hdsrc,   // f16 H then D, contiguous (ws)
    const _Float16* __restrict__ wsw,     // f16 weight blob (ws)
    float* __restrict__ out) {
    const int tid  = threadIdx.x;
    const int lane = tid & 63;
    const int wv   = tid >> 6;
    const int q    = lane >> 4;
    const int c15  = lane & 15;

    __shared__ __align__(16) _Float16 fl[1024 * 28];      // feat: wave-private rows, 57.3 KB
    __shared__ __align__(16) _Float16 hdl[2 * AHALVES];   // H then D, 78.1 KB
    __shared__ __align__(16) _Float16 wl[WTOT];           // 7.4 KB

    // ---- stage H+D (5000 uint4, coalesced) + weights; ONE barrier ----
    {
        const uint4* src = (const uint4*)hdsrc;
        uint4* dst = (uint4*)hdl;
        for (int i = tid; i < (2 * AHALVES) / 8; i += 1024) dst[i] = src[i];
        if (tid < 472) ((uint4*)wl)[tid] = ((const uint4*)wsw)[tid];
    }
    __syncthreads();

    const _Float16* hp  = hdl;
    const _Float16* dp  = hdl + AHALVES;
    const _Float16* wb  = fl + (size_t)wv * 64 * 28;
    const _Float16* w0l = wl + W0OFF;
    const _Float16* w1l = wl + W1OFF;
    const _Float16* w2l = wl + W2OFF;
    const _Float16* w3l = wl + W3OFF;
    const size_t blkbase = (size_t)blockIdx.x * (1024 * K);

    auto xload = [&](int it, float2& a, float2& b, float2& c) {
        const float2* p = (const float2*)(x + (blkbase + (size_t)it * 1024 + tid) * 6);
        a = p[0]; b = p[1]; c = p[2];
    };

    // ---- prologue: x[0], gU[0]+U-loads[0], x[1] ----
    float2 xc01, xc23, xc45;   // x of current iter
    float2 xn01, xn23, xn45;   // x of next iter
    xload(0, xc01, xc23, xc45);
    if (K > 1) xload(1, xn01, xn23, xn45);

    GA gUc = mkU(xc01.x, xc01.y);
    half8 tU0 = *(const half8*)(up + gUc.o0);
    half8 tU1 = *(const half8*)(up + gUc.o1);
    half8 tU2 = *(const half8*)(up + gUc.o2);
    half8 tU3 = *(const half8*)(up + gUc.o3);
    __builtin_amdgcn_sched_barrier(0);

#pragma unroll
    for (int it = 0; it < K; ++it) {
        // ---- prefetch: U of it+1 (from xn), x of it+2 ----
        GA gUn;
        half8 mU0, mU1, mU2, mU3;
        float2 x201, x223, x245;
        if (it + 1 < K) {
            gUn = mkU(xn01.x, xn01.y);
            mU0 = *(const half8*)(up + gUn.o0);
            mU1 = *(const half8*)(up + gUn.o1);
            mU2 = *(const half8*)(up + gUn.o2);
            mU3 = *(const half8*)(up + gUn.o3);
        }
        if (it + 2 < K) xload(it + 2, x201, x223, x245);
        __builtin_amdgcn_sched_barrier(0);

        // ---- current iter: H/D addr + LDS gathers ----
        GA gH = mkA(xc23.y, xc23.x);
        GA gD = mkA(xc45.y, xc45.x);
        half8 tH0 = *(const half8*)(hp + gH.o0);
        half8 tH1 = *(const half8*)(hp + gH.o1);
        half8 tH2 = *(const half8*)(hp + gH.o2);
        half8 tH3 = *(const half8*)(hp + gH.o3);
        half8 tD0 = *(const half8*)(dp + gD.o0);
        half8 tD1 = *(const half8*)(dp + gD.o1);
        half8 tD2 = *(const half8*)(dp + gD.o2);
        half8 tD3 = *(const half8*)(dp + gD.o3);

        // ---- bilerp (exact verified per-channel FMA order) ----
        float fU[8], fH[8], fD[8];
        blend8(tH0, tH1, tH2, tH3, gH, fH);
        blend8(tD0, tD1, tD2, tD3, gD, fD);
        blend8(tU0, tU1, tU2, tU3, gUc, fU);

        // ---- feat -> f16 -> LDS (row = my point; wave-private slice) ----
        {
            _Float16* row = fl + tid * 28;
            half8 hU, hH, hD;
#pragma unroll
            for (int i = 0; i < 8; ++i) {
                hU[i] = (_Float16)fU[i];
                hH[i] = (_Float16)fH[i];
                hD[i] = (_Float16)fD[i];
            }
            *(half8*)(row)      = hU;   // ch 0-7
            *(half8*)(row + 8)  = hH;   // ch 8-15
            *(half8*)(row + 16) = hD;   // ch 16-23
        }
        // wave-local handoff (same-wave lockstep; verified R8..R17)
        asm volatile("s_waitcnt lgkmcnt(0)" ::: "memory");
        __builtin_amdgcn_sched_barrier(0);

        // ---- MLP: wave owns 64 points, j-tiles {0..3} ----
        floatx4 zf; zf[0] = 0.f; zf[1] = 0.f; zf[2] = 0.f; zf[3] = 0.f;
        half4 b0[4], b1[4];
#pragma unroll
        for (int j = 0; j < 4; ++j) {
            const _Float16* r = wb + (size_t)(j * 16 + c15) * 28;
            b0[j] = *(const half4*)(r + q * 4);
            b1[j] = (q < 2) ? *(const half4*)(r + 16 + q * 4) : zero4();
        }

        floatx4 cc[2][4];
        // layer 0 (K=24: k-half1 zero for q>=2 on both operands; W0 stride 28)
#pragma unroll
        for (int m = 0; m < 2; ++m) {
            half4 a0 = *(const half4*)(w0l + (size_t)(16 * m + c15) * 28 + q * 4);
            half4 a1 = (q < 2) ? *(const half4*)(w0l + (size_t)(16 * m + c15) * 28 + 16 + q * 4) : zero4();
#pragma unroll
            for (int j = 0; j < 4; ++j)
                cc[m][j] = mfma16(a1, b1[j], mfma16(a0, b0[j], zf));
        }
#pragma unroll
        for (int j = 0; j < 4; ++j) {
#pragma unroll
            for (int e = 0; e < 4; ++e) {
                b0[j][e] = (_Float16)cc[0][j][e];
                b1[j][e] = (_Float16)cc[1][j][e];
            }
            b0[j] = relu4(b0[j]);
            b1[j] = relu4(b1[j]);
        }

        // layer 1
#pragma unroll
        for (int m = 0; m < 2; ++m) {
            half4 a0 = *(const half4*)(w1l + (size_t)(16 * m + c15) * 36 + q * 4);
            half4 a1 = *(const half4*)(w1l + (size_t)(16 * m + c15) * 36 + 16 + q * 4);
#pragma unroll
            for (int j = 0; j < 4; ++j)
                cc[m][j] = mfma16(a1, b1[j], mfma16(a0, b0[j], zf));
        }
#pragma unroll
        for (int j = 0; j < 4; ++j) {
#pragma unroll
            for (int e = 0; e < 4; ++e) {
                b0[j][e] = (_Float16)cc[0][j][e];
                b1[j][e] = (_Float16)cc[1][j][e];
            }
            b0[j] = relu4(b0[j]);
            b1[j] = relu4(b1[j]);
        }

        // layer 2
#pragma unroll
        for (int m = 0; m < 2; ++m) {
            half4 a0 = *(const half4*)(w2l + (size_t)(16 * m + c15) * 36 + q * 4);
            half4 a1 = *(const half4*)(w2l + (size_t)(16 * m + c15) * 36 + 16 + q * 4);
#pragma unroll
            for (int j = 0; j < 4; ++j)
                cc[m][j] = mfma16(a1, b1[j], mfma16(a0, b0[j], zf));
        }
#pragma unroll
        for (int j = 0; j < 4; ++j) {
#pragma unroll
            for (int e = 0; e < 4; ++e) {
                b0[j][e] = (_Float16)cc[0][j][e];
                b1[j][e] = (_Float16)cc[1][j][e];
            }
            b0[j] = relu4(b0[j]);
            b1[j] = relu4(b1[j]);
        }

        // layer 3 (rows 0-2 valid; w3l rows 3-15 zero)
        floatx4 c3[4];
        {
            half4 a0 = *(const half4*)(w3l + (size_t)c15 * 36 + q * 4);
            half4 a1 = *(const half4*)(w3l + (size_t)c15 * 36 + 16 + q * 4);
#pragma unroll
            for (int j = 0; j < 4; ++j)
                c3[j] = mfma16(a1, b1[j], mfma16(a0, b0[j], zf));
        }

        if (lane < 16) {
            const size_t base = blkbase + (size_t)it * 1024 + (size_t)wv * 64;
#pragma unroll
            for (int j = 0; j < 4; ++j) {
                size_t p = base + (size_t)j * 16 + lane;
                float* o = out + p * 3;
                o[0] = c3[j][0];
                o[1] = c3[j][1];
                o[2] = c3[j][2];
            }
        }

        // ---- rotate pipeline state ----
        if (it + 1 < K) {
            xc01 = xn01; xc23 = xn23; xc45 = xn45;
            xn01 = x201; xn23 = x223; xn45 = x245;
            gUc = gUn;
            tU0 = mU0; tU1 = mU1; tU2 = mU2; tU3 = mU3;
        }
    }
}

// ---- fallback (f32 planes, R13 structure; only if ws too small) ----
__global__ __launch_bounds__(512, 2) void tpmlp_f32(
    const float* __restrict__ x,
    const float* __restrict__ up,
    const float* __restrict__ hp,
    const float* __restrict__ dp,
    const _Float16* __restrict__ wsw,
    float* __restrict__ out) {
    const int tid  = threadIdx.x;
    const int lane = tid & 63;
    const int wv   = tid >> 6;
    const int q    = lane >> 4;
    const int c15  = lane & 15;

    __shared__ __align__(16) _Float16 fl[512 * 28];
    __shared__ __align__(16) _Float16 wl[WTOT];

    const size_t P = (size_t)blockIdx.x * 512 + tid;
    const float2* xp = (const float2*)(x + P * 6);
    float2 p01v = xp[0], p23v = xp[1], p45v = xp[2];

    uint4 w_a;
    if (tid < 472) w_a = ((const uint4*)wsw)[tid];

    GA gU = mkU(p01v.x, p01v.y);
    GA gH = mkA(p23v.y, p23v.x);
    GA gD = mkA(p45v.y, p45v.x);

    float4 sU0 = *(const float4*)(up + gU.o0); float4 rU0 = *(const float4*)(up + gU.o0 + 4);
    float4 sU1 = *(const float4*)(up + gU.o1); float4 rU1 = *(const float4*)(up + gU.o1 + 4);
    float4 sU2 = *(const float4*)(up + gU.o2); float4 rU2 = *(const float4*)(up + gU.o2 + 4);
    float4 sU3 = *(const float4*)(up + gU.o3); float4 rU3 = *(const float4*)(up + gU.o3 + 4);
    float4 sH0 = *(const float4*)(hp + gH.o0); float4 rH0 = *(const float4*)(hp + gH.o0 + 4);
    float4 sH1 = *(const float4*)(hp + gH.o1); float4 rH1 = *(const float4*)(hp + gH.o1 + 4);
    float4 sH2 = *(const float4*)(hp + gH.o2); float4 rH2 = *(const float4*)(hp + gH.o2 + 4);
    float4 sH3 = *(const float4*)(hp + gH.o3); float4 rH3 = *(const float4*)(hp + gH.o3 + 4);
    float4 sD0 = *(const float4*)(dp + gD.o0); float4 rD0 = *(const float4*)(dp + gD.o0 + 4);
    float4 sD1 = *(const float4*)(dp + gD.o1); float4 rD1 = *(const float4*)(dp + gD.o1 + 4);
    float4 sD2 = *(const float4*)(dp + gD.o2); float4 rD2 = *(const float4*)(dp + gD.o2 + 4);
    float4 sD3 = *(const float4*)(dp + gD.o3); float4 rD3 = *(const float4*)(dp + gD.o3 + 4);
    __builtin_amdgcn_sched_barrier(0);

    if (tid < 472) ((uint4*)wl)[tid] = w_a;
    asm volatile("s_waitcnt lgkmcnt(0)" ::: "memory");
    __builtin_amdgcn_s_barrier();

    float fU[8], fH[8], fD[8];
#pragma unroll
    for (int i = 0; i < 8; ++i) {
        const float* a = i < 4 ? (const float*)&sU0 : (const float*)&rU0;
        const float* b = i < 4 ? (const float*)&sU1 : (const float*)&rU1;
        const float* c = i < 4 ? (const float*)&sU2 : (const float*)&rU2;
        const float* d = i < 4 ? (const float*)&sU3 : (const float*)&rU3;
        int k = i & 3;
        float r = a[k] * gU.w00;
        r = fmaf(b[k], gU.w10, r);
        r = fmaf(c[k], gU.w01, r);
        r = fmaf(d[k], gU.w11, r);
        fU[i] = r;
    }
#pragma unroll
    for (int i = 0; i < 8; ++i) {
        const float* a = i < 4 ? (const float*)&sH0 : (const float*)&rH0;
        const float* b = i < 4 ? (const float*)&sH1 : (const float*)&rH1;
        const float* c = i < 4 ? (const float*)&sH2 : (const float*)&rH2;
        const float* d = i < 4 ? (const float*)&sH3 : (const float*)&rH3;
        int k = i & 3;
        float r = a[k] * gH.w00;
        r = fmaf(b[k], gH.w10, r);
        r = fmaf(c[k], gH.w01, r);
        r = fmaf(d[k], gH.w11, r);
        fH[i] = r;
    }
#pragma unroll
    for (int i = 0; i < 8; ++i) {
        const float* a = i < 4 ? (const float*)&sD0 : (const float*)&rD0;
        const float* b = i < 4 ? (const float*)&sD1 : (const float*)&rD1;
        const float* c = i < 4 ? (const float*)&sD2 : (const float*)&rD2;
        const float* d = i < 4 ? (const float*)&sD3 : (const float*)&rD3;
        int k = i & 3;
        float r = a[k] * gD.w00;
        r = fmaf(b[k], gD.w10, r);
        r = fmaf(c[k], gD.w01, r);
        r = fmaf(d[k], gD.w11, r);
        fD[i] = r;
    }

    {
        _Float16* row = fl + tid * 28;
        half8 hU, hH, hD;
#pragma unroll
        for (int i = 0; i < 8; ++i) {
            hU[i] = (_Float16)fU[i];
            hH[i] = (_Float16)fH[i];
            hD[i] = (_Float16)fD[i];
        }
        *(half8*)(row)      = hU;
        *(half8*)(row + 8)  = hH;
        *(half8*)(row + 16) = hD;
    }
    asm volatile("s_waitcnt lgkmcnt(0)" ::: "memory");
    __builtin_amdgcn_sched_barrier(0);

    floatx4 zf; zf[0] = 0.f; zf[1] = 0.f; zf[2] = 0.f; zf[3] = 0.f;
    const _Float16* wb = fl + (size_t)wv * 64 * 28;
    const _Float16* w0l = wl + W0OFF;
    const _Float16* w1l = wl + W1OFF;
    const _Float16* w2l = wl + W2OFF;
    const _Float16* w3l = wl + W3OFF;

    half4 b0[4], b1[4];
#pragma unroll
    for (int j = 0; j < 4; ++j) {
        const _Float16* r = wb + (size_t)(j * 16 + c15) * 28;
        b0[j] = *(const half4*)(r + q * 4);
        b1[j] = (q < 2) ? *(const half4*)(r + 16 + q * 4) : zero4();
    }

    floatx4 cc[2][4];
#pragma unroll
    for (int m = 0; m < 2; ++m) {
        half4 a0 = *(const half4*)(w0l + (size_t)(16 * m + c15) * 28 + q * 4);
        half4 a1 = (q < 2) ? *(const half4*)(w0l + (size_t)(16 * m + c15) * 28 + 16 + q * 4) : zero4();
#pragma unroll
        for (int j = 0; j < 4; ++j)
            cc[m][j] = mfma16(a1, b1[j], mfma16(a0, b0[j], zf));
    }
#pragma unroll
    for (int j = 0; j < 4; ++j) {
#pragma unroll
        for (int e = 0; e < 4; ++e) {
            b0[j][e] = (_Float16)cc[0][j][e];
            b1[j][e] = (_Float16)cc[1][j][e];
        }
        b0[j] = relu4(b0[j]);
        b1[j] = relu4(b1[j]);
    }
#pragma unroll
    for (int m = 0; m < 2; ++m) {
        half4 a0 = *(const half4*)(w1l + (size_t)(16 * m + c15) * 36 + q * 4);
        half4 a1 = *(const half4*)(w1l + (size_t)(16 * m + c15) * 36 + 16 + q * 4);
#pragma unroll
        for (int j = 0; j < 4; ++j)
            cc[m][j] = mfma16(a1, b1[j], mfma16(a0, b0[j], zf));
    }
#pragma unroll
    for (int j = 0; j < 4; ++j) {
#pragma unroll
        for (int e = 0; e < 4; ++e) {
            b0[j][e] = (_Float16)cc[0][j][e];
            b1[j][e] = (_Float16)cc[1][j][e];
        }
        b0[j] = relu4(b0[j]);
        b1[j] = relu4(b1[j]);
    }
#pragma unroll
    for (int m = 0; m < 2; ++m) {
        half4 a0 = *(const half4*)(w2l + (size_t)(16 * m + c15) * 36 + q * 4);
        half4 a1 = *(const half4*)(w2l + (size_t)(16 * m + c15) * 36 + 16 + q * 4);
#pragma unroll
        for (int j = 0; j < 4; ++j)
            cc[m][j] = mfma16(a1, b1[j], mfma16(a0, b0[j], zf));
    }
#pragma unroll
    for (int j = 0; j < 4; ++j) {
#pragma unroll
        for (int e = 0; e < 4; ++e) {
            b0[j][e] = (_Float16)cc[0][j][e];
            b1[j][e] = (_Float16)cc[1][j][e];
        }
        b0[j] = relu4(b0[j]);
        b1[j] = relu4(b1[j]);
    }

    floatx4 c3[4];
    {
        half4 a0 = *(const half4*)(w3l + (size_t)c15 * 36 + q * 4);
        half4 a1 = *(const half4*)(w3l + (size_t)c15 * 36 + 16 + q * 4);
#pragma unroll
        for (int j = 0; j < 4; ++j)
            c3[j] = mfma16(a1, b1[j], mfma16(a0, b0[j], zf));
    }

    if (lane < 16) {
        const size_t base = (size_t)blockIdx.x * 512 + (size_t)wv * 64;
#pragma unroll
        for (int j = 0; j < 4; ++j) {
            size_t p = base + (size_t)j * 16 + lane;
            float* o = out + p * 3;
            o[0] = c3[j][0];
            o[1] = c3[j][1];
            o[2] = c3[j][2];
        }
    }
}

extern "C" void kernel_launch(void* const* d_in, const int* in_sizes, int n_in,
                              void* d_out, int out_size, void* d_ws, size_t ws_size,
                              hipStream_t stream) {
    const float* x       = (const float*)d_in[0];
    const float* u_plane = (const float*)d_in[1];
    const float* h_plane = (const float*)d_in[2];
    const float* d_plane = (const float*)d_in[3];
    const float* W0      = (const float*)d_in[4];
    const float* W1      = (const float*)d_in[5];
    const float* W2      = (const float*)d_in[6];
    const float* W3      = (const float*)d_in[7];
    float* out = (float*)d_out;
    _Float16* wsw = (_Float16*)d_ws;

    int n = in_sizes[0] / 6;          // 2^21
    constexpr int K = 4;

    const size_t need = ((size_t)WOFF + WTOT) * 2;
    if (ws_size >= need) {
        pconv_kernel<<<648, 256, 0, stream>>>(u_plane, h_plane, d_plane,
                                              W0, W1, W2, W3, wsw);
        int grid = n / (1024 * K);    // 512 blocks
        tpmlp_kernel<K><<<grid, 1024, 0, stream>>>(
            x, wsw, wsw + UHALVES, wsw + WOFF, out);
    } else {
        wprep_kernel<<<1, 256, 0, stream>>>(W0, W1, W2, W3, wsw);
        tpmlp_f32<<<n / 512, 512, 0, stream>>>(
            x, u_plane, h_plane, d_plane, wsw, out);
    }
}